// Round 4
// baseline (529.225 us; speedup 1.0000x reference)
//
#include <hip/hip_runtime.h>

// Problem constants
constexpr int Bsz = 4, Ssz = 2048, Dsz = 1024, Hn = 16, dh = 64, An = 256;

typedef __attribute__((ext_vector_type(8))) short bf16x8;
typedef __attribute__((ext_vector_type(4))) float f32x4;

// ---------- helpers ----------
__device__ __forceinline__ unsigned short f2bf_rn(float f) {
    unsigned int u = __float_as_uint(f);
    return (unsigned short)((u + 0x7FFFu + ((u >> 16) & 1u)) >> 16);
}
__device__ __forceinline__ float bf2f(unsigned short h) {
    return __uint_as_float(((unsigned int)h) << 16);
}
__device__ __forceinline__ void bf_split(float f, unsigned short& hi, unsigned short& lo) {
    hi = f2bf_rn(f);
    lo = f2bf_rn(f - bf2f(hi));
}
__device__ __forceinline__ void gload16(const unsigned short* g, unsigned short* l) {
    __builtin_amdgcn_global_load_lds(
        (const __attribute__((address_space(1))) unsigned int*)g,
        (__attribute__((address_space(3))) unsigned int*)l, 16, 0, 0);
}
__device__ __forceinline__ bf16x8 gfrag(const unsigned short* g) {
    return *reinterpret_cast<const bf16x8*>(g);
}

// Read one 16-row x 32-k fragment (k-step ks) from a [*][ROWLEN] bf16 LDS tile
// written with chunk-XOR swizzle (chunk ^= row&7).
template<int ROWLEN>
__device__ __forceinline__ bf16x8 fragR(const unsigned short* buf, int row, int ks, int lane) {
    int c = ks * 4 + (lane >> 4);
    int cs = (c ^ (row & 7)) & (ROWLEN / 8 - 1);
    return *reinterpret_cast<const bf16x8*>(buf + row * ROWLEN + cs * 8);
}

// fp32 [n4*4] -> bf16 hi/lo arrays
__global__ __launch_bounds__(256)
void split_kernel(const float* __restrict__ x, unsigned short* __restrict__ hi,
                  unsigned short* __restrict__ lo, int n4)
{
    int i = blockIdx.x * 256 + threadIdx.x;
    if (i >= n4) return;
    float4 v = reinterpret_cast<const float4*>(x)[i];
    ushort4 h, l;
    bf_split(v.x, h.x, l.x);
    bf_split(v.y, h.y, l.y);
    bf_split(v.z, h.z, l.z);
    bf_split(v.w, h.w, l.w);
    reinterpret_cast<ushort4*>(hi)[i] = h;
    reinterpret_cast<ushort4*>(lo)[i] = l;
}

// ---------- split-bf16 MFMA GEMM: C[m,n] = sum_k A[m,k]*B[n,k] + bias[n] ----------
// OMODE 0: fp32 flat [M][N]. OMODE 1: split bf16 head-split [B,H,S,dh].
// OMODE 2: split bf16 head-split TRANSPOSED [B,H,dh,S].
#define MT 128
#define BKm 32

__device__ __forceinline__ bf16x8 lds_frag(const unsigned short* buf, int baseRow, int lane) {
    int row = baseRow + (lane & 15);
    int c = lane >> 4;
    int idx = row * 32 + ((c ^ ((row >> 1) & 3)) << 3);
    return *reinterpret_cast<const bf16x8*>(buf + idx);
}

template<int OMODE>
__global__ __launch_bounds__(256, 2)
void gemm_nt_mfma3(const unsigned short* __restrict__ Ahi, const unsigned short* __restrict__ Alo,
                   const unsigned short* __restrict__ Bhi, const unsigned short* __restrict__ Blo,
                   const float* __restrict__ bias, float* __restrict__ Cf,
                   unsigned short* __restrict__ Chi, unsigned short* __restrict__ Clo,
                   int K, int N)
{
    __shared__ unsigned short lds[4 * 4096];
    const int t = threadIdx.x;
    const int lane = t & 63, wid = t >> 6;
    const int wr = wid >> 1, wc = wid & 1;
    const int m0 = blockIdx.y * MT, n0 = blockIdx.x * MT;

    const int srow0 = t >> 2;
    const int x4 = t & 3;
    const int ldsBase0 = (wid * 64) * 8;
    const int ldsBase1 = (256 + wid * 64) * 8;

    f32x4 acc[4][4];
    #pragma unroll
    for (int i = 0; i < 4; ++i)
        #pragma unroll
        for (int j = 0; j < 4; ++j)
            acc[i][j] = f32x4{0.f, 0.f, 0.f, 0.f};

    const unsigned short* gA[2] = {Ahi, Alo};
    const unsigned short* gB[2] = {Bhi, Blo};

    for (int k0 = 0; k0 < K; k0 += BKm) {
        #pragma unroll
        for (int hb = 0; hb < 2; ++hb) {
            {
                const unsigned short* G = gA[hb];
                int r0 = srow0, r1 = srow0 + 64;
                int c0 = x4 ^ ((r0 >> 1) & 3);
                int c1 = x4 ^ ((r1 >> 1) & 3);
                gload16(G + (size_t)(m0 + r0) * K + k0 + c0 * 8, lds + hb * 4096 + ldsBase0);
                gload16(G + (size_t)(m0 + r1) * K + k0 + c1 * 8, lds + hb * 4096 + ldsBase1);
            }
            {
                const unsigned short* G = gB[hb];
                int r0 = srow0, r1 = srow0 + 64;
                int c0 = x4 ^ ((r0 >> 1) & 3);
                int c1 = x4 ^ ((r1 >> 1) & 3);
                gload16(G + (size_t)(n0 + r0) * K + k0 + c0 * 8, lds + (2 + hb) * 4096 + ldsBase0);
                gload16(G + (size_t)(n0 + r1) * K + k0 + c1 * 8, lds + (2 + hb) * 4096 + ldsBase1);
            }
        }
        __syncthreads();

        bf16x8 ah[4], al[4], bh[4], bl[4];
        #pragma unroll
        for (int mi = 0; mi < 4; ++mi) {
            ah[mi] = lds_frag(lds + 0 * 4096, wr * 64 + mi * 16, lane);
            al[mi] = lds_frag(lds + 1 * 4096, wr * 64 + mi * 16, lane);
        }
        #pragma unroll
        for (int ni = 0; ni < 4; ++ni) {
            bh[ni] = lds_frag(lds + 2 * 4096, wc * 64 + ni * 16, lane);
            bl[ni] = lds_frag(lds + 3 * 4096, wc * 64 + ni * 16, lane);
        }
        #pragma unroll
        for (int mi = 0; mi < 4; ++mi)
            #pragma unroll
            for (int ni = 0; ni < 4; ++ni) {
                acc[mi][ni] = __builtin_amdgcn_mfma_f32_16x16x32_bf16(ah[mi], bh[ni], acc[mi][ni], 0, 0, 0);
                acc[mi][ni] = __builtin_amdgcn_mfma_f32_16x16x32_bf16(ah[mi], bl[ni], acc[mi][ni], 0, 0, 0);
                acc[mi][ni] = __builtin_amdgcn_mfma_f32_16x16x32_bf16(al[mi], bh[ni], acc[mi][ni], 0, 0, 0);
            }
        __syncthreads();
    }

    #pragma unroll
    for (int mi = 0; mi < 4; ++mi) {
        #pragma unroll
        for (int ni = 0; ni < 4; ++ni) {
            const int n = n0 + wc * 64 + ni * 16 + (lane & 15);
            const float bval = bias[n];
            #pragma unroll
            for (int j = 0; j < 4; ++j) {
                const int m = m0 + wr * 64 + mi * 16 + ((lane >> 4) << 2) + j;
                float val = acc[mi][ni][j] + bval;
                if constexpr (OMODE == 0) {
                    Cf[(size_t)m * N + n] = val;
                } else {
                    const int b = m >> 11, s = m & (Ssz - 1);
                    const int h = n >> 6, c = n & (dh - 1);
                    size_t idx;
                    if constexpr (OMODE == 1)
                        idx = (((size_t)(b * Hn + h)) * Ssz + s) * dh + c;
                    else
                        idx = (((size_t)(b * Hn + h)) * dh + c) * Ssz + s;
                    unsigned short hi, lo;
                    bf_split(val, hi, lo);
                    Chi[idx] = hi; Clo[idx] = lo;
                }
            }
        }
    }
}

// ---------- agent pooling ----------
__global__ __launch_bounds__(256)
void pool_agent(const unsigned short* __restrict__ qh_hi, const unsigned short* __restrict__ qh_lo,
                unsigned short* __restrict__ ag_hi, unsigned short* __restrict__ ag_lo)
{
    const int idx = blockIdx.x * 256 + threadIdx.x;
    const int c = idx & (dh - 1);
    const int a = (idx >> 6) & (An - 1);
    const int bh = idx >> 14;
    const size_t base = ((size_t)bh * Ssz + a * 8) * dh + c;
    float s = 0.f;
    #pragma unroll
    for (int j = 0; j < 8; ++j)
        s += bf2f(qh_hi[base + j * dh]) + bf2f(qh_lo[base + j * dh]);
    s *= 0.125f;
    unsigned short hi, lo;
    bf_split(s, hi, lo);
    ag_hi[idx] = hi; ag_lo[idx] = lo;
}

// ---------- flash stage-1 (v2): direct-load operands, split-S across waves ----------
// grid (An/16, B*H) = (16, 64). block 256 = 4 waves; wave w owns s in [w*512, w*512+512).
__global__ __launch_bounds__(256, 3)
void flash1(const unsigned short* __restrict__ ag_hi, const unsigned short* __restrict__ ag_lo,
            const unsigned short* __restrict__ kh_hi, const unsigned short* __restrict__ kh_lo,
            const unsigned short* __restrict__ vt_hi, const unsigned short* __restrict__ vt_lo,
            unsigned short* __restrict__ avt_hi, unsigned short* __restrict__ avt_lo)
{
    __shared__ unsigned short pbuf[4][2][1024];   // per-wave P [16 a][64 s] hi/lo (16 KB)
    __shared__ float obuf[4][16][64];             // per-wave O [a][d] (16 KB)
    __shared__ float mlbuf[4][2][16];             // per-wave m,l per agent

    const int t = threadIdx.x, lane = t & 63, w = t >> 6;
    const int al15 = lane & 15, hi4 = lane >> 4;
    const int bh = blockIdx.y, a0 = blockIdx.x * 16;

    // agent (Q) fragments for this block's 16 agents — direct global, hoisted
    const size_t agoff = ((size_t)bh * An + a0 + al15) * dh;
    bf16x8 bqh[2], bql[2];
    #pragma unroll
    for (int ks = 0; ks < 2; ++ks) {
        bqh[ks] = gfrag(ag_hi + agoff + ks * 32 + hi4 * 8);
        bql[ks] = gfrag(ag_lo + agoff + ks * 32 + hi4 * 8);
    }

    unsigned short* pwh = pbuf[w][0];
    unsigned short* pwl = pbuf[w][1];

    f32x4 O[4];
    #pragma unroll
    for (int i = 0; i < 4; ++i) O[i] = f32x4{0.f, 0.f, 0.f, 0.f};
    float m_run = -INFINITY, l_run = 0.f;

    for (int it = 0; it < 8; ++it) {
        const int s0 = w * 512 + it * 64;

        // QK^T (swapped): acc col = agent, row = s
        f32x4 sc[4];
        #pragma unroll
        for (int si = 0; si < 4; ++si) sc[si] = f32x4{0.f, 0.f, 0.f, 0.f};
        #pragma unroll
        for (int si = 0; si < 4; ++si) {
            const size_t koff = ((size_t)bh * Ssz + s0 + si * 16 + al15) * dh;
            #pragma unroll
            for (int ks = 0; ks < 2; ++ks) {
                bf16x8 ah = gfrag(kh_hi + koff + ks * 32 + hi4 * 8);
                bf16x8 al = gfrag(kh_lo + koff + ks * 32 + hi4 * 8);
                sc[si] = __builtin_amdgcn_mfma_f32_16x16x32_bf16(ah, bqh[ks], sc[si], 0, 0, 0);
                sc[si] = __builtin_amdgcn_mfma_f32_16x16x32_bf16(ah, bql[ks], sc[si], 0, 0, 0);
                sc[si] = __builtin_amdgcn_mfma_f32_16x16x32_bf16(al, bqh[ks], sc[si], 0, 0, 0);
            }
        }

        // online softmax over s for agent = lane&15
        float tmax = -INFINITY;
        #pragma unroll
        for (int si = 0; si < 4; ++si)
            #pragma unroll
            for (int j = 0; j < 4; ++j) {
                sc[si][j] *= 0.125f;
                tmax = fmaxf(tmax, sc[si][j]);
            }
        tmax = fmaxf(tmax, __shfl_xor(tmax, 16));
        tmax = fmaxf(tmax, __shfl_xor(tmax, 32));
        float newm = fmaxf(m_run, tmax);
        float fac = __expf(m_run - newm);
        float tsum = 0.f;
        #pragma unroll
        for (int si = 0; si < 4; ++si)
            #pragma unroll
            for (int j = 0; j < 4; ++j) {
                float p = __expf(sc[si][j] - newm);
                sc[si][j] = p;
                tsum += p;
            }
        tsum += __shfl_xor(tsum, 16);
        tsum += __shfl_xor(tsum, 32);
        l_run = l_run * fac + tsum;
        m_run = newm;

        // P -> per-wave LDS [a][s], chunk-XOR swizzled
        #pragma unroll
        for (int si = 0; si < 4; ++si) {
            ushort4 h4, l4;
            bf_split(sc[si][0], h4.x, l4.x);
            bf_split(sc[si][1], h4.y, l4.y);
            bf_split(sc[si][2], h4.z, l4.z);
            bf_split(sc[si][3], h4.w, l4.w);
            int baseS = si * 16 + (hi4 << 2);
            int addr = al15 * 64 + (baseS ^ ((al15 & 7) << 3));
            *reinterpret_cast<ushort4*>(pwh + addr) = h4;
            *reinterpret_cast<ushort4*>(pwl + addr) = l4;
        }
        __syncthreads();   // ordering safety (uniform; P is per-wave)

        // rescale O by fac of agent a=(hi4*4+j)
        float fj[4];
        #pragma unroll
        for (int j = 0; j < 4; ++j) fj[j] = __shfl(fac, (hi4 << 2) + j);
        #pragma unroll
        for (int di = 0; di < 4; ++di)
            #pragma unroll
            for (int j = 0; j < 4; ++j) O[di][j] *= fj[j];

        // PV: O[a][d] += P[a][s] * Vt[d][s]  (Vt direct global)
        #pragma unroll
        for (int ks = 0; ks < 2; ++ks) {
            bf16x8 pah = fragR<64>(pwh, al15, ks, lane);
            bf16x8 pal = fragR<64>(pwl, al15, ks, lane);
            #pragma unroll
            for (int di = 0; di < 4; ++di) {
                const size_t voff = ((size_t)bh * dh + di * 16 + al15) * Ssz + s0 + ks * 32 + hi4 * 8;
                bf16x8 vh = gfrag(vt_hi + voff);
                bf16x8 vl = gfrag(vt_lo + voff);
                O[di] = __builtin_amdgcn_mfma_f32_16x16x32_bf16(pah, vh, O[di], 0, 0, 0);
                O[di] = __builtin_amdgcn_mfma_f32_16x16x32_bf16(pah, vl, O[di], 0, 0, 0);
                O[di] = __builtin_amdgcn_mfma_f32_16x16x32_bf16(pal, vh, O[di], 0, 0, 0);
            }
        }
        __syncthreads();
    }

    // cross-wave flash merge
    #pragma unroll
    for (int di = 0; di < 4; ++di)
        #pragma unroll
        for (int j = 0; j < 4; ++j)
            obuf[w][(hi4 << 2) + j][di * 16 + al15] = O[di][j];
    if (lane < 16) {
        mlbuf[w][0][lane] = m_run;
        mlbuf[w][1][lane] = l_run;
    }
    __syncthreads();

    const int d = t >> 2;
    const int ab = (t & 3) << 2;
    unsigned short th[4], tl[4];
    #pragma unroll
    for (int i = 0; i < 4; ++i) {
        const int a = ab + i;
        float ms = fmaxf(fmaxf(mlbuf[0][0][a], mlbuf[1][0][a]),
                         fmaxf(mlbuf[2][0][a], mlbuf[3][0][a]));
        float lsum = 0.f, val = 0.f;
        #pragma unroll
        for (int w2 = 0; w2 < 4; ++w2) {
            float f = __expf(mlbuf[w2][0][a] - ms);
            lsum += f * mlbuf[w2][1][a];
            val  += f * obuf[w2][a][d];
        }
        val /= lsum;
        bf_split(val, th[i], tl[i]);
    }
    const size_t oidx = ((size_t)bh * dh + d) * An + a0 + ab;
    *reinterpret_cast<ushort4*>(avt_hi + oidx) = ushort4{th[0], th[1], th[2], th[3]};
    *reinterpret_cast<ushort4*>(avt_lo + oidx) = ushort4{tl[0], tl[1], tl[2], tl[3]};
}

// ---------- flash stage-2 (v2): direct-load operands; LDS = P only ----------
// grid (Ssz/64, B*H). block 256 (4 waves x 16 s-rows).
__global__ __launch_bounds__(256, 2)
void flash2(const unsigned short* __restrict__ qh_hi, const unsigned short* __restrict__ qh_lo,
            const unsigned short* __restrict__ ag_hi, const unsigned short* __restrict__ ag_lo,
            const unsigned short* __restrict__ avt_hi, const unsigned short* __restrict__ avt_lo,
            float* __restrict__ q_attn,
            unsigned short* __restrict__ xo_hi, unsigned short* __restrict__ xo_lo)
{
    __shared__ unsigned short pbuf[4][2][4096];   // per-wave P [16 s][256 a] hi/lo (64 KB)

    const int t = threadIdx.x, lane = t & 63, w = t >> 6;
    const int al15 = lane & 15, hi4 = lane >> 4;
    const int bh = blockIdx.y;
    const int s0 = blockIdx.x * 64;

    unsigned short* pwh = pbuf[w][0];
    unsigned short* pwl = pbuf[w][1];

    // qh (Q) fragments — direct global
    const size_t qoff = ((size_t)bh * Ssz + s0 + w * 16 + al15) * dh;
    bf16x8 bqh[2], bql[2];
    #pragma unroll
    for (int ks = 0; ks < 2; ++ks) {
        bqh[ks] = gfrag(qh_hi + qoff + ks * 32 + hi4 * 8);
        bql[ks] = gfrag(qh_lo + qoff + ks * 32 + hi4 * 8);
    }

    // QK^T (swapped): acc col = s, rows = a; agents direct from global (L2-resident)
    f32x4 acc[16];
    #pragma unroll
    for (int ai = 0; ai < 16; ++ai) acc[ai] = f32x4{0.f, 0.f, 0.f, 0.f};
    #pragma unroll
    for (int ai = 0; ai < 16; ++ai) {
        const size_t aoff = ((size_t)bh * An + ai * 16 + al15) * dh;
        #pragma unroll
        for (int ks = 0; ks < 2; ++ks) {
            bf16x8 ah = gfrag(ag_hi + aoff + ks * 32 + hi4 * 8);
            bf16x8 al = gfrag(ag_lo + aoff + ks * 32 + hi4 * 8);
            acc[ai] = __builtin_amdgcn_mfma_f32_16x16x32_bf16(ah, bqh[ks], acc[ai], 0, 0, 0);
            acc[ai] = __builtin_amdgcn_mfma_f32_16x16x32_bf16(ah, bql[ks], acc[ai], 0, 0, 0);
            acc[ai] = __builtin_amdgcn_mfma_f32_16x16x32_bf16(al, bqh[ks], acc[ai], 0, 0, 0);
        }
    }

    // exact softmax over a for s = lane&15
    float mx = -INFINITY;
    #pragma unroll
    for (int ai = 0; ai < 16; ++ai)
        #pragma unroll
        for (int j = 0; j < 4; ++j) {
            acc[ai][j] *= 0.125f;
            mx = fmaxf(mx, acc[ai][j]);
        }
    mx = fmaxf(mx, __shfl_xor(mx, 16));
    mx = fmaxf(mx, __shfl_xor(mx, 32));
    float sum = 0.f;
    #pragma unroll
    for (int ai = 0; ai < 16; ++ai)
        #pragma unroll
        for (int j = 0; j < 4; ++j) {
            float p = __expf(acc[ai][j] - mx);
            acc[ai][j] = p;
            sum += p;
        }
    sum += __shfl_xor(sum, 16);
    sum += __shfl_xor(sum, 32);
    const float inv = 1.0f / sum;

    // write q_attn (fp32) + P into per-wave LDS
    {
        const int sG = s0 + w * 16 + al15;
        float* qrow = q_attn + ((size_t)bh * Ssz + sG) * An;
        #pragma unroll
        for (int ai = 0; ai < 16; ++ai) {
            float4 o;
            o.x = acc[ai][0] * inv; o.y = acc[ai][1] * inv;
            o.z = acc[ai][2] * inv; o.w = acc[ai][3] * inv;
            *reinterpret_cast<float4*>(qrow + ai * 16 + (hi4 << 2)) = o;
            ushort4 h4, l4;
            bf_split(o.x, h4.x, l4.x);
            bf_split(o.y, h4.y, l4.y);
            bf_split(o.z, h4.z, l4.z);
            bf_split(o.w, h4.w, l4.w);
            int baseA = ai * 16 + (hi4 << 2);
            int addr = al15 * 256 + (baseA ^ ((al15 & 7) << 3));
            *reinterpret_cast<ushort4*>(pwh + addr) = h4;
            *reinterpret_cast<ushort4*>(pwl + addr) = l4;
        }
    }
    __syncthreads();

    // PV: O[s][d] = sum_a P[s][a] * avt[d][a]  (avt direct global)
    f32x4 O[4];
    #pragma unroll
    for (int i = 0; i < 4; ++i) O[i] = f32x4{0.f, 0.f, 0.f, 0.f};
    #pragma unroll
    for (int ks = 0; ks < 8; ++ks) {
        bf16x8 pah = fragR<256>(pwh, al15, ks, lane);
        bf16x8 pal = fragR<256>(pwl, al15, ks, lane);
        #pragma unroll
        for (int di = 0; di < 4; ++di) {
            const size_t voff = ((size_t)bh * dh + di * 16 + al15) * An + ks * 32 + hi4 * 8;
            bf16x8 avh = gfrag(avt_hi + voff);
            bf16x8 avl = gfrag(avt_lo + voff);
            O[di] = __builtin_amdgcn_mfma_f32_16x16x32_bf16(pah, avh, O[di], 0, 0, 0);
            O[di] = __builtin_amdgcn_mfma_f32_16x16x32_bf16(pah, avl, O[di], 0, 0, 0);
            O[di] = __builtin_amdgcn_mfma_f32_16x16x32_bf16(pal, avh, O[di], 0, 0, 0);
        }
    }

    // epilogue: out_h split bf16 into [B,S,D] head-merged
    const int b = bh >> 4, h = bh & (Hn - 1);
    #pragma unroll
    for (int di = 0; di < 4; ++di)
        #pragma unroll
        for (int j = 0; j < 4; ++j) {
            float val = O[di][j];
            int sG = s0 + w * 16 + (hi4 << 2) + j;
            int dfull = h * dh + di * 16 + al15;
            size_t idx = ((size_t)b * Ssz + sG) * Dsz + dfull;
            unsigned short hi, lo;
            bf_split(val, hi, lo);
            xo_hi[idx] = hi; xo_lo[idx] = lo;
        }
}

extern "C" void kernel_launch(void* const* d_in, const int* in_sizes, int n_in,
                              void* d_out, int out_size, void* d_ws, size_t ws_size,
                              hipStream_t stream)
{
    const float* q  = (const float*)d_in[0];
    const float* k  = (const float*)d_in[1];
    const float* v  = (const float*)d_in[2];
    const float* Wq = (const float*)d_in[3];
    const float* bq = (const float*)d_in[4];
    const float* Wk = (const float*)d_in[5];
    const float* bk = (const float*)d_in[6];
    const float* Wv = (const float*)d_in[7];
    const float* bv = (const float*)d_in[8];
    const float* Wo = (const float*)d_in[9];
    const float* bo = (const float*)d_in[10];

    constexpr size_t BSD = (size_t)Bsz * Ssz * Dsz;    // 8,388,608
    constexpr size_t DD  = (size_t)Dsz * Dsz;          // 1,048,576
    constexpr size_t AGD = (size_t)Bsz * Hn * An * dh; // 1,048,576

    float* out    = (float*)d_out;
    float* q_attn = out + BSD;

    unsigned short* u = (unsigned short*)d_ws;
    unsigned short* x_hi   = u;                 // [B,S,D] bf16 (also out_h buffer)
    unsigned short* x_lo   = x_hi + BSD;
    unsigned short* qh_hi  = x_lo + BSD;        // [B,H,S,dh]
    unsigned short* qh_lo  = qh_hi + BSD;
    unsigned short* kh_hi  = qh_lo + BSD;
    unsigned short* kh_lo  = kh_hi + BSD;
    unsigned short* vt_hi  = kh_lo + BSD;       // [B,H,dh,S]
    unsigned short* vt_lo  = vt_hi + BSD;
    unsigned short* w_hi   = vt_lo + BSD;       // [D,D]
    unsigned short* w_lo   = w_hi + DD;
    unsigned short* ag_hi  = w_lo + DD;         // [B,H,A,dh]
    unsigned short* ag_lo  = ag_hi + AGD;
    unsigned short* avt_hi = ag_lo + AGD;       // [B,H,dh,A]
    unsigned short* avt_lo = avt_hi + AGD;

    const int M = Bsz * Ssz;                    // 8192
    dim3 gmfma(Dsz / MT, M / MT, 1);            // (8, 64)

    // Q projection
    split_kernel<<<BSD / 1024, 256, 0, stream>>>(q, x_hi, x_lo, BSD / 4);
    split_kernel<<<DD / 1024, 256, 0, stream>>>(Wq, w_hi, w_lo, DD / 4);
    gemm_nt_mfma3<1><<<gmfma, 256, 0, stream>>>(x_hi, x_lo, w_hi, w_lo, bq, nullptr, qh_hi, qh_lo, Dsz, Dsz);
    // K projection
    split_kernel<<<BSD / 1024, 256, 0, stream>>>(k, x_hi, x_lo, BSD / 4);
    split_kernel<<<DD / 1024, 256, 0, stream>>>(Wk, w_hi, w_lo, DD / 4);
    gemm_nt_mfma3<1><<<gmfma, 256, 0, stream>>>(x_hi, x_lo, w_hi, w_lo, bk, nullptr, kh_hi, kh_lo, Dsz, Dsz);
    // V projection (transposed head-split output)
    split_kernel<<<BSD / 1024, 256, 0, stream>>>(v, x_hi, x_lo, BSD / 4);
    split_kernel<<<DD / 1024, 256, 0, stream>>>(Wv, w_hi, w_lo, DD / 4);
    gemm_nt_mfma3<2><<<gmfma, 256, 0, stream>>>(x_hi, x_lo, w_hi, w_lo, bv, nullptr, vt_hi, vt_lo, Dsz, Dsz);

    // agent pooling (split output)
    pool_agent<<<AGD / 256, 256, 0, stream>>>(qh_hi, qh_lo, ag_hi, ag_lo);

    // stage 1: flash agent attention -> agent_v^T
    flash1<<<dim3(An / 16, Bsz * Hn), 256, 0, stream>>>(
        ag_hi, ag_lo, kh_hi, kh_lo, vt_hi, vt_lo, avt_hi, avt_lo);

    // stage 2: q attends agents -> q_attn (output) + out_h (split, into x buffer)
    flash2<<<dim3(Ssz / 64, Bsz * Hn), 256, 0, stream>>>(
        qh_hi, qh_lo, ag_hi, ag_lo, avt_hi, avt_lo, q_attn, x_hi, x_lo);

    // output projection
    split_kernel<<<DD / 1024, 256, 0, stream>>>(Wo, w_hi, w_lo, DD / 4);
    gemm_nt_mfma3<0><<<gmfma, 256, 0, stream>>>(x_hi, x_lo, w_hi, w_lo, bo, out, nullptr, nullptr, Dsz, Dsz);
}

// Round 5
// 446.651 us; speedup vs baseline: 1.1849x; 1.1849x over previous
//
#include <hip/hip_runtime.h>

// Problem constants
constexpr int Bsz = 4, Ssz = 2048, Dsz = 1024, Hn = 16, dh = 64, An = 256;

typedef __attribute__((ext_vector_type(8))) short bf16x8;
typedef __attribute__((ext_vector_type(4))) float f32x4;

// ---------- helpers ----------
__device__ __forceinline__ unsigned short f2bf_rn(float f) {
    unsigned int u = __float_as_uint(f);
    return (unsigned short)((u + 0x7FFFu + ((u >> 16) & 1u)) >> 16);
}
__device__ __forceinline__ float bf2f(unsigned short h) {
    return __uint_as_float(((unsigned int)h) << 16);
}
__device__ __forceinline__ void bf_split(float f, unsigned short& hi, unsigned short& lo) {
    hi = f2bf_rn(f);
    lo = f2bf_rn(f - bf2f(hi));
}
__device__ __forceinline__ void gload16(const unsigned short* g, unsigned short* l) {
    __builtin_amdgcn_global_load_lds(
        (const __attribute__((address_space(1))) unsigned int*)g,
        (__attribute__((address_space(3))) unsigned int*)l, 16, 0, 0);
}
__device__ __forceinline__ bf16x8 gfrag(const unsigned short* g) {
    return *reinterpret_cast<const bf16x8*>(g);
}

// Stage a tile of rows x (8*2^LOGC elems) into linear LDS with source-side
// chunk swizzle (chunk_src = c ^ (row&7)); fragR reads with the same XOR.
template<int LOGC, int NISS>
__device__ __forceinline__ void stage_tile(const unsigned short* __restrict__ g, long rowStride,
                                           unsigned short* lbase, int t) {
    const int wid = t >> 6;
    #pragma unroll
    for (int i = 0; i < NISS; ++i) {
        int slot = i * 256 + t;
        int r = slot >> LOGC;
        int c = slot & ((1 << LOGC) - 1);
        int cs = (c ^ (r & 7)) & ((1 << LOGC) - 1);
        gload16(g + (long)r * rowStride + cs * 8, lbase + (i * 256 + wid * 64) * 8);
    }
}

// Read one 16-row x 32-k fragment (k-step ks) from a [*][ROWLEN] bf16 LDS tile.
template<int ROWLEN>
__device__ __forceinline__ bf16x8 fragR(const unsigned short* buf, int row, int ks, int lane) {
    int c = ks * 4 + (lane >> 4);
    int cs = (c ^ (row & 7)) & (ROWLEN / 8 - 1);
    return *reinterpret_cast<const bf16x8*>(buf + row * ROWLEN + cs * 8);
}

// fp32 [n4*4] -> bf16 hi/lo arrays
__global__ __launch_bounds__(256)
void split_kernel(const float* __restrict__ x, unsigned short* __restrict__ hi,
                  unsigned short* __restrict__ lo, int n4)
{
    int i = blockIdx.x * 256 + threadIdx.x;
    if (i >= n4) return;
    float4 v = reinterpret_cast<const float4*>(x)[i];
    ushort4 h, l;
    bf_split(v.x, h.x, l.x);
    bf_split(v.y, h.y, l.y);
    bf_split(v.z, h.z, l.z);
    bf_split(v.w, h.w, l.w);
    reinterpret_cast<ushort4*>(hi)[i] = h;
    reinterpret_cast<ushort4*>(lo)[i] = l;
}

// ---------- split-bf16 MFMA GEMM: C[m,n] = sum_k A[m,k]*B[n,k] + bias[n] ----------
// OMODE 0: fp32 flat [M][N]. OMODE 1: split bf16 head-split [B,H,S,dh].
// OMODE 2: split bf16 head-split TRANSPOSED [B,H,dh,S].
#define MT 128
#define BKm 32

__device__ __forceinline__ bf16x8 lds_frag(const unsigned short* buf, int baseRow, int lane) {
    int row = baseRow + (lane & 15);
    int c = lane >> 4;
    int idx = row * 32 + ((c ^ ((row >> 1) & 3)) << 3);
    return *reinterpret_cast<const bf16x8*>(buf + idx);
}

template<int OMODE>
__global__ __launch_bounds__(256, 2)
void gemm_nt_mfma3(const unsigned short* __restrict__ Ahi, const unsigned short* __restrict__ Alo,
                   const unsigned short* __restrict__ Bhi, const unsigned short* __restrict__ Blo,
                   const float* __restrict__ bias, float* __restrict__ Cf,
                   unsigned short* __restrict__ Chi, unsigned short* __restrict__ Clo,
                   int K, int N)
{
    __shared__ unsigned short lds[4 * 4096];
    const int t = threadIdx.x;
    const int lane = t & 63, wid = t >> 6;
    const int wr = wid >> 1, wc = wid & 1;
    const int m0 = blockIdx.y * MT, n0 = blockIdx.x * MT;

    const int srow0 = t >> 2;
    const int x4 = t & 3;
    const int ldsBase0 = (wid * 64) * 8;
    const int ldsBase1 = (256 + wid * 64) * 8;

    f32x4 acc[4][4];
    #pragma unroll
    for (int i = 0; i < 4; ++i)
        #pragma unroll
        for (int j = 0; j < 4; ++j)
            acc[i][j] = f32x4{0.f, 0.f, 0.f, 0.f};

    const unsigned short* gA[2] = {Ahi, Alo};
    const unsigned short* gB[2] = {Bhi, Blo};

    for (int k0 = 0; k0 < K; k0 += BKm) {
        #pragma unroll
        for (int hb = 0; hb < 2; ++hb) {
            {
                const unsigned short* G = gA[hb];
                int r0 = srow0, r1 = srow0 + 64;
                int c0 = x4 ^ ((r0 >> 1) & 3);
                int c1 = x4 ^ ((r1 >> 1) & 3);
                gload16(G + (size_t)(m0 + r0) * K + k0 + c0 * 8, lds + hb * 4096 + ldsBase0);
                gload16(G + (size_t)(m0 + r1) * K + k0 + c1 * 8, lds + hb * 4096 + ldsBase1);
            }
            {
                const unsigned short* G = gB[hb];
                int r0 = srow0, r1 = srow0 + 64;
                int c0 = x4 ^ ((r0 >> 1) & 3);
                int c1 = x4 ^ ((r1 >> 1) & 3);
                gload16(G + (size_t)(n0 + r0) * K + k0 + c0 * 8, lds + (2 + hb) * 4096 + ldsBase0);
                gload16(G + (size_t)(n0 + r1) * K + k0 + c1 * 8, lds + (2 + hb) * 4096 + ldsBase1);
            }
        }
        __syncthreads();

        bf16x8 ah[4], al[4], bh[4], bl[4];
        #pragma unroll
        for (int mi = 0; mi < 4; ++mi) {
            ah[mi] = lds_frag(lds + 0 * 4096, wr * 64 + mi * 16, lane);
            al[mi] = lds_frag(lds + 1 * 4096, wr * 64 + mi * 16, lane);
        }
        #pragma unroll
        for (int ni = 0; ni < 4; ++ni) {
            bh[ni] = lds_frag(lds + 2 * 4096, wc * 64 + ni * 16, lane);
            bl[ni] = lds_frag(lds + 3 * 4096, wc * 64 + ni * 16, lane);
        }
        #pragma unroll
        for (int mi = 0; mi < 4; ++mi)
            #pragma unroll
            for (int ni = 0; ni < 4; ++ni) {
                acc[mi][ni] = __builtin_amdgcn_mfma_f32_16x16x32_bf16(ah[mi], bh[ni], acc[mi][ni], 0, 0, 0);
                acc[mi][ni] = __builtin_amdgcn_mfma_f32_16x16x32_bf16(ah[mi], bl[ni], acc[mi][ni], 0, 0, 0);
                acc[mi][ni] = __builtin_amdgcn_mfma_f32_16x16x32_bf16(al[mi], bh[ni], acc[mi][ni], 0, 0, 0);
            }
        __syncthreads();
    }

    #pragma unroll
    for (int mi = 0; mi < 4; ++mi) {
        #pragma unroll
        for (int ni = 0; ni < 4; ++ni) {
            const int n = n0 + wc * 64 + ni * 16 + (lane & 15);
            const float bval = bias[n];
            #pragma unroll
            for (int j = 0; j < 4; ++j) {
                const int m = m0 + wr * 64 + mi * 16 + ((lane >> 4) << 2) + j;
                float val = acc[mi][ni][j] + bval;
                if constexpr (OMODE == 0) {
                    Cf[(size_t)m * N + n] = val;
                } else {
                    const int b = m >> 11, s = m & (Ssz - 1);
                    const int h = n >> 6, c = n & (dh - 1);
                    size_t idx;
                    if constexpr (OMODE == 1)
                        idx = (((size_t)(b * Hn + h)) * Ssz + s) * dh + c;
                    else
                        idx = (((size_t)(b * Hn + h)) * dh + c) * Ssz + s;
                    unsigned short hi, lo;
                    bf_split(val, hi, lo);
                    Chi[idx] = hi; Clo[idx] = lo;
                }
            }
        }
    }
}

// ---------- agent pooling ----------
__global__ __launch_bounds__(256)
void pool_agent(const unsigned short* __restrict__ qh_hi, const unsigned short* __restrict__ qh_lo,
                unsigned short* __restrict__ ag_hi, unsigned short* __restrict__ ag_lo)
{
    const int idx = blockIdx.x * 256 + threadIdx.x;
    const int c = idx & (dh - 1);
    const int a = (idx >> 6) & (An - 1);
    const int bh = idx >> 14;
    const size_t base = ((size_t)bh * Ssz + a * 8) * dh + c;
    float s = 0.f;
    #pragma unroll
    for (int j = 0; j < 8; ++j)
        s += bf2f(qh_hi[base + j * dh]) + bf2f(qh_lo[base + j * dh]);
    s *= 0.125f;
    unsigned short hi, lo;
    bf_split(s, hi, lo);
    ag_hi[idx] = hi; ag_lo[idx] = lo;
}

// ---------- flash stage-1 (R3 structure): 64-agent blocks, K/V LDS-staged ----------
// grid (An/64, B*H) = (4, 64). block 256 (4 waves x 16 agents).
__global__ __launch_bounds__(256, 2)
void flash1(const unsigned short* __restrict__ ag_hi, const unsigned short* __restrict__ ag_lo,
            const unsigned short* __restrict__ kh_hi, const unsigned short* __restrict__ kh_lo,
            const unsigned short* __restrict__ vt_hi_g, const unsigned short* __restrict__ vt_lo_g,
            unsigned short* __restrict__ avt_hi, unsigned short* __restrict__ avt_lo)
{
    __shared__ unsigned short lds[32768];   // 64 KB
    unsigned short* agh = lds;              // [64][64]
    unsigned short* agl = lds + 4096;
    unsigned short* kth = lds + 8192;       // [64][64]
    unsigned short* ktl = lds + 12288;
    unsigned short* vth = lds + 16384;      // [64 d][64 s]
    unsigned short* vtl = lds + 20480;
    const int t = threadIdx.x;
    const int lane = t & 63, w = t >> 6;
    unsigned short* pwh = lds + 24576 + w * 2048;   // per-wave P [16 a][64 s]
    unsigned short* pwl = pwh + 1024;

    const int bh = blockIdx.y;
    const int a0 = blockIdx.x * 64;

    stage_tile<3, 2>(ag_hi + ((size_t)bh * An + a0) * dh, dh, agh, t);
    stage_tile<3, 2>(ag_lo + ((size_t)bh * An + a0) * dh, dh, agl, t);

    f32x4 O[4];
    #pragma unroll
    for (int i = 0; i < 4; ++i) O[i] = f32x4{0.f, 0.f, 0.f, 0.f};
    float m_run = -INFINITY, l_run = 0.f;

    bf16x8 bqh[2], bql[2];
    bool haveQ = false;

    for (int s0 = 0; s0 < Ssz; s0 += 64) {
        stage_tile<3, 2>(kh_hi + ((size_t)bh * Ssz + s0) * dh, dh, kth, t);
        stage_tile<3, 2>(kh_lo + ((size_t)bh * Ssz + s0) * dh, dh, ktl, t);
        stage_tile<3, 2>(vt_hi_g + (size_t)bh * dh * Ssz + s0, Ssz, vth, t);
        stage_tile<3, 2>(vt_lo_g + (size_t)bh * dh * Ssz + s0, Ssz, vtl, t);
        __syncthreads();

        if (!haveQ) {
            #pragma unroll
            for (int ks = 0; ks < 2; ++ks) {
                bqh[ks] = fragR<64>(agh, w * 16 + (lane & 15), ks, lane);
                bql[ks] = fragR<64>(agl, w * 16 + (lane & 15), ks, lane);
            }
            haveQ = true;
        }

        // QK^T (swapped): acc col = agent (lane&15), row = s
        f32x4 sc[4];
        #pragma unroll
        for (int si = 0; si < 4; ++si) sc[si] = f32x4{0.f, 0.f, 0.f, 0.f};
        #pragma unroll
        for (int si = 0; si < 4; ++si)
            #pragma unroll
            for (int ks = 0; ks < 2; ++ks) {
                bf16x8 ah = fragR<64>(kth, si * 16 + (lane & 15), ks, lane);
                bf16x8 al = fragR<64>(ktl, si * 16 + (lane & 15), ks, lane);
                sc[si] = __builtin_amdgcn_mfma_f32_16x16x32_bf16(ah, bqh[ks], sc[si], 0, 0, 0);
                sc[si] = __builtin_amdgcn_mfma_f32_16x16x32_bf16(ah, bql[ks], sc[si], 0, 0, 0);
                sc[si] = __builtin_amdgcn_mfma_f32_16x16x32_bf16(al, bqh[ks], sc[si], 0, 0, 0);
            }

        // online softmax over s for agent = lane&15
        float tmax = -INFINITY;
        #pragma unroll
        for (int si = 0; si < 4; ++si)
            #pragma unroll
            for (int j = 0; j < 4; ++j) {
                sc[si][j] *= 0.125f;
                tmax = fmaxf(tmax, sc[si][j]);
            }
        tmax = fmaxf(tmax, __shfl_xor(tmax, 16));
        tmax = fmaxf(tmax, __shfl_xor(tmax, 32));
        float newm = fmaxf(m_run, tmax);
        float fac = __expf(m_run - newm);
        float tsum = 0.f;
        #pragma unroll
        for (int si = 0; si < 4; ++si)
            #pragma unroll
            for (int j = 0; j < 4; ++j) {
                float p = __expf(sc[si][j] - newm);
                sc[si][j] = p;
                tsum += p;
            }
        tsum += __shfl_xor(tsum, 16);
        tsum += __shfl_xor(tsum, 32);
        l_run = l_run * fac + tsum;
        m_run = newm;

        // write P (transposed into [a][s]) packed b64, swizzled
        const int aloc = lane & 15;
        #pragma unroll
        for (int si = 0; si < 4; ++si) {
            ushort4 h4, l4;
            bf_split(sc[si][0], h4.x, l4.x);
            bf_split(sc[si][1], h4.y, l4.y);
            bf_split(sc[si][2], h4.z, l4.z);
            bf_split(sc[si][3], h4.w, l4.w);
            int baseS = si * 16 + ((lane >> 4) << 2);
            int addr = aloc * 64 + (baseS ^ ((aloc & 7) << 3));
            *reinterpret_cast<ushort4*>(pwh + addr) = h4;
            *reinterpret_cast<ushort4*>(pwl + addr) = l4;
        }

        // rescale O
        float fj[4];
        #pragma unroll
        for (int j = 0; j < 4; ++j) fj[j] = __shfl(fac, ((lane >> 4) << 2) + j);
        #pragma unroll
        for (int di = 0; di < 4; ++di)
            #pragma unroll
            for (int j = 0; j < 4; ++j) O[di][j] *= fj[j];

        // PV: O[a][d] += P[a][s] * Vt[d][s]
        #pragma unroll
        for (int ks = 0; ks < 2; ++ks) {
            bf16x8 pah = fragR<64>(pwh, lane & 15, ks, lane);
            bf16x8 pal = fragR<64>(pwl, lane & 15, ks, lane);
            #pragma unroll
            for (int di = 0; di < 4; ++di) {
                bf16x8 vh = fragR<64>(vth, di * 16 + (lane & 15), ks, lane);
                bf16x8 vl = fragR<64>(vtl, di * 16 + (lane & 15), ks, lane);
                O[di] = __builtin_amdgcn_mfma_f32_16x16x32_bf16(pah, vh, O[di], 0, 0, 0);
                O[di] = __builtin_amdgcn_mfma_f32_16x16x32_bf16(pah, vl, O[di], 0, 0, 0);
                O[di] = __builtin_amdgcn_mfma_f32_16x16x32_bf16(pal, vh, O[di], 0, 0, 0);
            }
        }
        __syncthreads();
    }

    // epilogue: normalize, write agent_v transposed [bh][d][a] split bf16
    float lj[4];
    #pragma unroll
    for (int j = 0; j < 4; ++j) lj[j] = __shfl(l_run, ((lane >> 4) << 2) + j);
    #pragma unroll
    for (int di = 0; di < 4; ++di)
        #pragma unroll
        for (int j = 0; j < 4; ++j) {
            float val = O[di][j] / lj[j];
            int d = di * 16 + (lane & 15);
            int aG = a0 + w * 16 + ((lane >> 4) << 2) + j;
            size_t idx = ((size_t)bh * dh + d) * An + aG;
            unsigned short hi, lo;
            bf_split(val, hi, lo);
            avt_hi[idx] = hi; avt_lo[idx] = lo;
        }
}

// ---------- flash stage-2 (v3): agents LDS-staged; P reuses agents LDS; 64 KB ----------
// grid (Ssz/64, B*H). block 256 (4 waves x 16 s-rows).
__global__ __launch_bounds__(256, 2)
void flash2(const unsigned short* __restrict__ qh_hi, const unsigned short* __restrict__ qh_lo,
            const unsigned short* __restrict__ ag_hi, const unsigned short* __restrict__ ag_lo,
            const unsigned short* __restrict__ avt_hi, const unsigned short* __restrict__ avt_lo,
            float* __restrict__ q_attn,
            unsigned short* __restrict__ xo_hi, unsigned short* __restrict__ xo_lo)
{
    __shared__ unsigned short lds[32768];   // 64 KB
    unsigned short* agh = lds;              // [256][64] agents hi
    unsigned short* agl = lds + 16384;      // [256][64] agents lo

    const int t = threadIdx.x, lane = t & 63, w = t >> 6;
    const int al15 = lane & 15, hi4 = lane >> 4;
    const int bh = blockIdx.y;
    const int s0 = blockIdx.x * 64;

    // per-wave P region overlays the agents region after the QK barrier
    unsigned short* pwh = lds + w * 8192;   // [16 s][256 a] hi
    unsigned short* pwl = pwh + 4096;       // lo

    // stage agents (shared by all waves)
    stage_tile<3, 8>(ag_hi + (size_t)bh * An * dh, dh, agh, t);
    stage_tile<3, 8>(ag_lo + (size_t)bh * An * dh, dh, agl, t);

    // qh (Q) fragments — direct global (4 x 16B per lane, one-shot)
    const size_t qoff = ((size_t)bh * Ssz + s0 + w * 16 + al15) * dh;
    bf16x8 bqh[2], bql[2];
    #pragma unroll
    for (int ks = 0; ks < 2; ++ks) {
        bqh[ks] = gfrag(qh_hi + qoff + ks * 32 + hi4 * 8);
        bql[ks] = gfrag(qh_lo + qoff + ks * 32 + hi4 * 8);
    }
    __syncthreads();   // agents staged

    // QK^T (swapped): acc col = s (lane&15), rows = a
    f32x4 acc[16];
    #pragma unroll
    for (int ai = 0; ai < 16; ++ai) acc[ai] = f32x4{0.f, 0.f, 0.f, 0.f};
    #pragma unroll
    for (int ai = 0; ai < 16; ++ai)
        #pragma unroll
        for (int ks = 0; ks < 2; ++ks) {
            bf16x8 ah = fragR<64>(agh, ai * 16 + al15, ks, lane);
            bf16x8 al = fragR<64>(agl, ai * 16 + al15, ks, lane);
            acc[ai] = __builtin_amdgcn_mfma_f32_16x16x32_bf16(ah, bqh[ks], acc[ai], 0, 0, 0);
            acc[ai] = __builtin_amdgcn_mfma_f32_16x16x32_bf16(ah, bql[ks], acc[ai], 0, 0, 0);
            acc[ai] = __builtin_amdgcn_mfma_f32_16x16x32_bf16(al, bqh[ks], acc[ai], 0, 0, 0);
        }

    // exact softmax over a for s = lane&15
    float mx = -INFINITY;
    #pragma unroll
    for (int ai = 0; ai < 16; ++ai)
        #pragma unroll
        for (int j = 0; j < 4; ++j) {
            acc[ai][j] *= 0.125f;
            mx = fmaxf(mx, acc[ai][j]);
        }
    mx = fmaxf(mx, __shfl_xor(mx, 16));
    mx = fmaxf(mx, __shfl_xor(mx, 32));
    float sum = 0.f;
    #pragma unroll
    for (int ai = 0; ai < 16; ++ai)
        #pragma unroll
        for (int j = 0; j < 4; ++j) {
            float p = __expf(acc[ai][j] - mx);
            acc[ai][j] = p;
            sum += p;
        }
    sum += __shfl_xor(sum, 16);
    sum += __shfl_xor(sum, 32);
    const float inv = 1.0f / sum;

    __syncthreads();   // all waves done reading agents LDS; P may overwrite

    // write q_attn (fp32, coalesced float4) and P into per-wave LDS
    {
        const int sG = s0 + w * 16 + al15;
        float* qrow = q_attn + ((size_t)bh * Ssz + sG) * An;
        #pragma unroll
        for (int ai = 0; ai < 16; ++ai) {
            float4 o;
            o.x = acc[ai][0] * inv; o.y = acc[ai][1] * inv;
            o.z = acc[ai][2] * inv; o.w = acc[ai][3] * inv;
            *reinterpret_cast<float4*>(qrow + ai * 16 + (hi4 << 2)) = o;
            ushort4 h4, l4;
            bf_split(o.x, h4.x, l4.x);
            bf_split(o.y, h4.y, l4.y);
            bf_split(o.z, h4.z, l4.z);
            bf_split(o.w, h4.w, l4.w);
            int baseA = ai * 16 + (hi4 << 2);
            int addr = al15 * 256 + (baseA ^ ((al15 & 7) << 3));
            *reinterpret_cast<ushort4*>(pwh + addr) = h4;
            *reinterpret_cast<ushort4*>(pwl + addr) = l4;
        }
    }

    // PV: O[s][d] = sum_a P[s][a] * avt[d][a]  (P per-wave LDS; avt direct global, L2-hot)
    f32x4 O[4];
    #pragma unroll
    for (int i = 0; i < 4; ++i) O[i] = f32x4{0.f, 0.f, 0.f, 0.f};
    #pragma unroll
    for (int ks = 0; ks < 8; ++ks) {
        bf16x8 pah = fragR<256>(pwh, al15, ks, lane);
        bf16x8 pal = fragR<256>(pwl, al15, ks, lane);
        #pragma unroll
        for (int di = 0; di < 4; ++di) {
            const size_t voff = ((size_t)bh * dh + di * 16 + al15) * An + ks * 32 + hi4 * 8;
            bf16x8 avh = gfrag(avt_hi + voff);
            bf16x8 avl = gfrag(avt_lo + voff);
            O[di] = __builtin_amdgcn_mfma_f32_16x16x32_bf16(pah, avh, O[di], 0, 0, 0);
            O[di] = __builtin_amdgcn_mfma_f32_16x16x32_bf16(pah, avl, O[di], 0, 0, 0);
            O[di] = __builtin_amdgcn_mfma_f32_16x16x32_bf16(pal, avh, O[di], 0, 0, 0);
        }
    }

    // epilogue: out_h split bf16 into [B,S,D] head-merged
    const int b = bh >> 4, h = bh & (Hn - 1);
    #pragma unroll
    for (int di = 0; di < 4; ++di)
        #pragma unroll
        for (int j = 0; j < 4; ++j) {
            float val = O[di][j];
            int sG = s0 + w * 16 + (hi4 << 2) + j;
            int dfull = h * dh + di * 16 + al15;
            size_t idx = ((size_t)b * Ssz + sG) * Dsz + dfull;
            unsigned short hi, lo;
            bf_split(val, hi, lo);
            xo_hi[idx] = hi; xo_lo[idx] = lo;
        }
}

extern "C" void kernel_launch(void* const* d_in, const int* in_sizes, int n_in,
                              void* d_out, int out_size, void* d_ws, size_t ws_size,
                              hipStream_t stream)
{
    const float* q  = (const float*)d_in[0];
    const float* k  = (const float*)d_in[1];
    const float* v  = (const float*)d_in[2];
    const float* Wq = (const float*)d_in[3];
    const float* bq = (const float*)d_in[4];
    const float* Wk = (const float*)d_in[5];
    const float* bk = (const float*)d_in[6];
    const float* Wv = (const float*)d_in[7];
    const float* bv = (const float*)d_in[8];
    const float* Wo = (const float*)d_in[9];
    const float* bo = (const float*)d_in[10];

    constexpr size_t BSD = (size_t)Bsz * Ssz * Dsz;    // 8,388,608
    constexpr size_t DD  = (size_t)Dsz * Dsz;          // 1,048,576
    constexpr size_t AGD = (size_t)Bsz * Hn * An * dh; // 1,048,576

    float* out    = (float*)d_out;
    float* q_attn = out + BSD;

    unsigned short* u = (unsigned short*)d_ws;
    unsigned short* x_hi   = u;                 // [B,S,D] bf16 (also out_h buffer)
    unsigned short* x_lo   = x_hi + BSD;
    unsigned short* qh_hi  = x_lo + BSD;        // [B,H,S,dh]
    unsigned short* qh_lo  = qh_hi + BSD;
    unsigned short* kh_hi  = qh_lo + BSD;
    unsigned short* kh_lo  = kh_hi + BSD;
    unsigned short* vt_hi  = kh_lo + BSD;       // [B,H,dh,S]
    unsigned short* vt_lo  = vt_hi + BSD;
    unsigned short* w_hi   = vt_lo + BSD;       // [D,D]
    unsigned short* w_lo   = w_hi + DD;
    unsigned short* ag_hi  = w_lo + DD;         // [B,H,A,dh]
    unsigned short* ag_lo  = ag_hi + AGD;
    unsigned short* avt_hi = ag_lo + AGD;       // [B,H,dh,A]
    unsigned short* avt_lo = avt_hi + AGD;

    const int M = Bsz * Ssz;                    // 8192
    dim3 gmfma(Dsz / MT, M / MT, 1);            // (8, 64)

    // Q projection
    split_kernel<<<BSD / 1024, 256, 0, stream>>>(q, x_hi, x_lo, BSD / 4);
    split_kernel<<<DD / 1024, 256, 0, stream>>>(Wq, w_hi, w_lo, DD / 4);
    gemm_nt_mfma3<1><<<gmfma, 256, 0, stream>>>(x_hi, x_lo, w_hi, w_lo, bq, nullptr, qh_hi, qh_lo, Dsz, Dsz);
    // K projection
    split_kernel<<<BSD / 1024, 256, 0, stream>>>(k, x_hi, x_lo, BSD / 4);
    split_kernel<<<DD / 1024, 256, 0, stream>>>(Wk, w_hi, w_lo, DD / 4);
    gemm_nt_mfma3<1><<<gmfma, 256, 0, stream>>>(x_hi, x_lo, w_hi, w_lo, bk, nullptr, kh_hi, kh_lo, Dsz, Dsz);
    // V projection (transposed head-split output)
    split_kernel<<<BSD / 1024, 256, 0, stream>>>(v, x_hi, x_lo, BSD / 4);
    split_kernel<<<DD / 1024, 256, 0, stream>>>(Wv, w_hi, w_lo, DD / 4);
    gemm_nt_mfma3<2><<<gmfma, 256, 0, stream>>>(x_hi, x_lo, w_hi, w_lo, bv, nullptr, vt_hi, vt_lo, Dsz, Dsz);

    // agent pooling (split output)
    pool_agent<<<AGD / 256, 256, 0, stream>>>(qh_hi, qh_lo, ag_hi, ag_lo);

    // stage 1: flash agent attention -> agent_v^T
    flash1<<<dim3(An / 64, Bsz * Hn), 256, 0, stream>>>(
        ag_hi, ag_lo, kh_hi, kh_lo, vt_hi, vt_lo, avt_hi, avt_lo);

    // stage 2: q attends agents -> q_attn (output) + out_h (split, into x buffer)
    flash2<<<dim3(Ssz / 64, Bsz * Hn), 256, 0, stream>>>(
        qh_hi, qh_lo, ag_hi, ag_lo, avt_hi, avt_lo, q_attn, x_hi, x_lo);

    // output projection
    split_kernel<<<DD / 1024, 256, 0, stream>>>(Wo, w_hi, w_lo, DD / 4);
    gemm_nt_mfma3<0><<<gmfma, 256, 0, stream>>>(x_hi, x_lo, w_hi, w_lo, bo, out, nullptr, nullptr, Dsz, Dsz);
}

// Round 6
// 416.701 us; speedup vs baseline: 1.2700x; 1.0719x over previous
//
#include <hip/hip_runtime.h>

// Problem constants
constexpr int Bsz = 4, Ssz = 2048, Dsz = 1024, Hn = 16, dh = 64, An = 256;

typedef __attribute__((ext_vector_type(8))) short bf16x8;
typedef __attribute__((ext_vector_type(4))) float f32x4;

// ---------- helpers ----------
__device__ __forceinline__ unsigned short f2bf_rn(float f) {
    unsigned int u = __float_as_uint(f);
    return (unsigned short)((u + 0x7FFFu + ((u >> 16) & 1u)) >> 16);
}
__device__ __forceinline__ float bf2f(unsigned short h) {
    return __uint_as_float(((unsigned int)h) << 16);
}
__device__ __forceinline__ void bf_split(float f, unsigned short& hi, unsigned short& lo) {
    hi = f2bf_rn(f);
    lo = f2bf_rn(f - bf2f(hi));
}
__device__ __forceinline__ void gload16(const unsigned short* g, unsigned short* l) {
    __builtin_amdgcn_global_load_lds(
        (const __attribute__((address_space(1))) unsigned int*)g,
        (__attribute__((address_space(3))) unsigned int*)l, 16, 0, 0);
}
__device__ __forceinline__ bf16x8 gfrag(const unsigned short* g) {
    return *reinterpret_cast<const bf16x8*>(g);
}
// split 8 fp32 (two float4) into hi/lo bf16x8 fragments
__device__ __forceinline__ void make8(float4 a, float4 b, bf16x8& hi8, bf16x8& lo8) {
    float v[8] = {a.x, a.y, a.z, a.w, b.x, b.y, b.z, b.w};
    #pragma unroll
    for (int i = 0; i < 8; ++i) {
        unsigned short h, l;
        bf_split(v[i], h, l);
        hi8[i] = (short)h; lo8[i] = (short)l;
    }
}

// Fragment-tile layout (per bh): element (row, k) of a [R][64] operand lives at
//   tile(row>>4, k>>5)*512 + ((k>>3)&3)*128 + (row&15)*8 + (k&7)
// so an MFMA fragment load = base + lane*8, one contiguous 1KB wave transaction.

// Stage a row-major tile into linear LDS with source-side chunk swizzle.
template<int LOGC, int NISS>
__device__ __forceinline__ void stage_tile(const unsigned short* __restrict__ g, long rowStride,
                                           unsigned short* lbase, int t) {
    const int wid = t >> 6;
    #pragma unroll
    for (int i = 0; i < NISS; ++i) {
        int slot = i * 256 + t;
        int r = slot >> LOGC;
        int c = slot & ((1 << LOGC) - 1);
        int cs = (c ^ (r & 7)) & ((1 << LOGC) - 1);
        gload16(g + (long)r * rowStride + cs * 8, lbase + (i * 256 + wid * 64) * 8);
    }
}
template<int ROWLEN>
__device__ __forceinline__ bf16x8 fragR(const unsigned short* buf, int row, int ks, int lane) {
    int c = ks * 4 + (lane >> 4);
    int cs = (c ^ (row & 7)) & (ROWLEN / 8 - 1);
    return *reinterpret_cast<const bf16x8*>(buf + row * ROWLEN + cs * 8);
}

// fp32 [n4*4] -> bf16 hi/lo arrays
__global__ __launch_bounds__(256)
void split_kernel(const float* __restrict__ x, unsigned short* __restrict__ hi,
                  unsigned short* __restrict__ lo, int n4)
{
    int i = blockIdx.x * 256 + threadIdx.x;
    if (i >= n4) return;
    float4 v = reinterpret_cast<const float4*>(x)[i];
    ushort4 h, l;
    bf_split(v.x, h.x, l.x);
    bf_split(v.y, h.y, l.y);
    bf_split(v.z, h.z, l.z);
    bf_split(v.w, h.w, l.w);
    reinterpret_cast<ushort4*>(hi)[i] = h;
    reinterpret_cast<ushort4*>(lo)[i] = l;
}

// ---------- split-bf16 MFMA GEMM ----------
// OMODE 0: fp32 flat. 1: bf16-split [B,H,S,dh]. 2: bf16-split [B,H,dh,S]. 3: bf16-split TILE (qh).
#define MT 128
#define BKm 32

__device__ __forceinline__ bf16x8 lds_frag(const unsigned short* buf, int baseRow, int lane) {
    int row = baseRow + (lane & 15);
    int c = lane >> 4;
    int idx = row * 32 + ((c ^ ((row >> 1) & 3)) << 3);
    return *reinterpret_cast<const bf16x8*>(buf + idx);
}

template<int OMODE>
__global__ __launch_bounds__(256, 2)
void gemm_nt_mfma3(const unsigned short* __restrict__ Ahi, const unsigned short* __restrict__ Alo,
                   const unsigned short* __restrict__ Bhi, const unsigned short* __restrict__ Blo,
                   const float* __restrict__ bias, float* __restrict__ Cf,
                   unsigned short* __restrict__ Chi, unsigned short* __restrict__ Clo,
                   int K, int N)
{
    __shared__ unsigned short lds[4 * 4096];
    const int t = threadIdx.x;
    const int lane = t & 63, wid = t >> 6;
    const int wr = wid >> 1, wc = wid & 1;
    const int m0 = blockIdx.y * MT, n0 = blockIdx.x * MT;

    const int srow0 = t >> 2;
    const int x4 = t & 3;
    const int ldsBase0 = (wid * 64) * 8;
    const int ldsBase1 = (256 + wid * 64) * 8;

    f32x4 acc[4][4];
    #pragma unroll
    for (int i = 0; i < 4; ++i)
        #pragma unroll
        for (int j = 0; j < 4; ++j)
            acc[i][j] = f32x4{0.f, 0.f, 0.f, 0.f};

    const unsigned short* gA[2] = {Ahi, Alo};
    const unsigned short* gB[2] = {Bhi, Blo};

    for (int k0 = 0; k0 < K; k0 += BKm) {
        #pragma unroll
        for (int hb = 0; hb < 2; ++hb) {
            {
                const unsigned short* G = gA[hb];
                int r0 = srow0, r1 = srow0 + 64;
                int c0 = x4 ^ ((r0 >> 1) & 3);
                int c1 = x4 ^ ((r1 >> 1) & 3);
                gload16(G + (size_t)(m0 + r0) * K + k0 + c0 * 8, lds + hb * 4096 + ldsBase0);
                gload16(G + (size_t)(m0 + r1) * K + k0 + c1 * 8, lds + hb * 4096 + ldsBase1);
            }
            {
                const unsigned short* G = gB[hb];
                int r0 = srow0, r1 = srow0 + 64;
                int c0 = x4 ^ ((r0 >> 1) & 3);
                int c1 = x4 ^ ((r1 >> 1) & 3);
                gload16(G + (size_t)(n0 + r0) * K + k0 + c0 * 8, lds + (2 + hb) * 4096 + ldsBase0);
                gload16(G + (size_t)(n0 + r1) * K + k0 + c1 * 8, lds + (2 + hb) * 4096 + ldsBase1);
            }
        }
        __syncthreads();

        bf16x8 ah[4], al[4], bh[4], bl[4];
        #pragma unroll
        for (int mi = 0; mi < 4; ++mi) {
            ah[mi] = lds_frag(lds + 0 * 4096, wr * 64 + mi * 16, lane);
            al[mi] = lds_frag(lds + 1 * 4096, wr * 64 + mi * 16, lane);
        }
        #pragma unroll
        for (int ni = 0; ni < 4; ++ni) {
            bh[ni] = lds_frag(lds + 2 * 4096, wc * 64 + ni * 16, lane);
            bl[ni] = lds_frag(lds + 3 * 4096, wc * 64 + ni * 16, lane);
        }
        #pragma unroll
        for (int mi = 0; mi < 4; ++mi)
            #pragma unroll
            for (int ni = 0; ni < 4; ++ni) {
                acc[mi][ni] = __builtin_amdgcn_mfma_f32_16x16x32_bf16(ah[mi], bh[ni], acc[mi][ni], 0, 0, 0);
                acc[mi][ni] = __builtin_amdgcn_mfma_f32_16x16x32_bf16(ah[mi], bl[ni], acc[mi][ni], 0, 0, 0);
                acc[mi][ni] = __builtin_amdgcn_mfma_f32_16x16x32_bf16(al[mi], bh[ni], acc[mi][ni], 0, 0, 0);
            }
        __syncthreads();
    }

    #pragma unroll
    for (int mi = 0; mi < 4; ++mi) {
        #pragma unroll
        for (int ni = 0; ni < 4; ++ni) {
            const int n = n0 + wc * 64 + ni * 16 + (lane & 15);
            const float bval = bias[n];
            #pragma unroll
            for (int j = 0; j < 4; ++j) {
                const int m = m0 + wr * 64 + mi * 16 + ((lane >> 4) << 2) + j;
                float val = acc[mi][ni][j] + bval;
                if constexpr (OMODE == 0) {
                    Cf[(size_t)m * N + n] = val;
                } else {
                    const int b = m >> 11, s = m & (Ssz - 1);
                    const int h = n >> 6, c = n & (dh - 1);
                    size_t idx;
                    if constexpr (OMODE == 1)
                        idx = (((size_t)(b * Hn + h)) * Ssz + s) * dh + c;
                    else if constexpr (OMODE == 2)
                        idx = (((size_t)(b * Hn + h)) * dh + c) * Ssz + s;
                    else  // 3: fragment-tile layout for qh
                        idx = (size_t)(b * Hn + h) * 131072
                            + (((s >> 4) * 2 + (c >> 5)) << 9)
                            + (((c >> 3) & 3) << 7) + ((s & 15) << 3) + (c & 7);
                    unsigned short hi, lo;
                    bf_split(val, hi, lo);
                    Chi[idx] = hi; Clo[idx] = lo;
                }
            }
        }
    }
}

// ---------- agent pooling: reads qh TILE, writes agents TILE ----------
__global__ __launch_bounds__(256)
void pool_agent(const unsigned short* __restrict__ qh_hi, const unsigned short* __restrict__ qh_lo,
                unsigned short* __restrict__ ag_hi, unsigned short* __restrict__ ag_lo)
{
    const int idx = blockIdx.x * 256 + threadIdx.x;
    const int c = idx & (dh - 1);
    const int a = (idx >> 6) & (An - 1);
    const int bh = idx >> 14;
    // qh tile address of (s = a*8, c)
    const size_t base = (size_t)bh * 131072
        + (((a >> 1) * 2 + (c >> 5)) << 9) + (((c >> 3) & 3) << 7)
        + ((8 * (a & 1)) << 3) + (c & 7);
    float s = 0.f;
    #pragma unroll
    for (int j = 0; j < 8; ++j)
        s += bf2f(qh_hi[base + j * 8]) + bf2f(qh_lo[base + j * 8]);
    s *= 0.125f;
    unsigned short hi, lo;
    bf_split(s, hi, lo);
    const size_t oidx = (size_t)bh * 16384
        + (((a >> 4) * 2 + (c >> 5)) << 9) + (((c >> 3) & 3) << 7)
        + ((a & 15) << 3) + (c & 7);
    ag_hi[oidx] = hi; ag_lo[oidx] = lo;
}

// ---------- flash stage-1: 64-agent blocks, K/V LDS-staged, agents TILE-direct ----------
// grid (An/64, B*H) = (4, 64). block 256 (4 waves x 16 agents).
__global__ __launch_bounds__(256, 3)
void flash1(const unsigned short* __restrict__ ag_hi, const unsigned short* __restrict__ ag_lo,
            const unsigned short* __restrict__ kh_hi, const unsigned short* __restrict__ kh_lo,
            const unsigned short* __restrict__ vt_hi_g, const unsigned short* __restrict__ vt_lo_g,
            unsigned short* __restrict__ avt_hi, unsigned short* __restrict__ avt_lo)
{
    __shared__ unsigned short lds[24576];   // 48 KB
    unsigned short* kth = lds;              // [64][64]
    unsigned short* ktl = lds + 4096;
    unsigned short* vth = lds + 8192;       // [64 d][64 s]
    unsigned short* vtl = lds + 12288;
    const int t = threadIdx.x;
    const int lane = t & 63, w = t >> 6;
    const int al15 = lane & 15, hi4 = lane >> 4;
    unsigned short* pwh = lds + 16384 + w * 2048;   // per-wave P [16 a][64 s]
    unsigned short* pwl = pwh + 1024;

    const int bh = blockIdx.y;
    const int a0 = blockIdx.x * 64;

    // agent fragments: direct from TILE layout (coalesced 1KB loads)
    bf16x8 bqh[2], bql[2];
    {
        const size_t abase = (size_t)bh * 16384 + (size_t)((a0 >> 4) + w) * 1024;
        #pragma unroll
        for (int ks = 0; ks < 2; ++ks) {
            bqh[ks] = gfrag(ag_hi + abase + ks * 512 + lane * 8);
            bql[ks] = gfrag(ag_lo + abase + ks * 512 + lane * 8);
        }
    }

    f32x4 O[4];
    #pragma unroll
    for (int i = 0; i < 4; ++i) O[i] = f32x4{0.f, 0.f, 0.f, 0.f};
    float m_run = -INFINITY, l_run = 0.f;

    for (int s0 = 0; s0 < Ssz; s0 += 64) {
        stage_tile<3, 2>(kh_hi + ((size_t)bh * Ssz + s0) * dh, dh, kth, t);
        stage_tile<3, 2>(kh_lo + ((size_t)bh * Ssz + s0) * dh, dh, ktl, t);
        stage_tile<3, 2>(vt_hi_g + (size_t)bh * dh * Ssz + s0, Ssz, vth, t);
        stage_tile<3, 2>(vt_lo_g + (size_t)bh * dh * Ssz + s0, Ssz, vtl, t);
        __syncthreads();

        // QK^T (swapped): acc col = agent (lane&15), row = s
        f32x4 sc[4];
        #pragma unroll
        for (int si = 0; si < 4; ++si) sc[si] = f32x4{0.f, 0.f, 0.f, 0.f};
        #pragma unroll
        for (int si = 0; si < 4; ++si)
            #pragma unroll
            for (int ks = 0; ks < 2; ++ks) {
                bf16x8 ah = fragR<64>(kth, si * 16 + al15, ks, lane);
                bf16x8 al = fragR<64>(ktl, si * 16 + al15, ks, lane);
                sc[si] = __builtin_amdgcn_mfma_f32_16x16x32_bf16(ah, bqh[ks], sc[si], 0, 0, 0);
                sc[si] = __builtin_amdgcn_mfma_f32_16x16x32_bf16(ah, bql[ks], sc[si], 0, 0, 0);
                sc[si] = __builtin_amdgcn_mfma_f32_16x16x32_bf16(al, bqh[ks], sc[si], 0, 0, 0);
            }

        // online softmax over s for agent = lane&15
        float tmax = -INFINITY;
        #pragma unroll
        for (int si = 0; si < 4; ++si)
            #pragma unroll
            for (int j = 0; j < 4; ++j) {
                sc[si][j] *= 0.125f;
                tmax = fmaxf(tmax, sc[si][j]);
            }
        tmax = fmaxf(tmax, __shfl_xor(tmax, 16));
        tmax = fmaxf(tmax, __shfl_xor(tmax, 32));
        float newm = fmaxf(m_run, tmax);
        float fac = __expf(m_run - newm);
        float tsum = 0.f;
        #pragma unroll
        for (int si = 0; si < 4; ++si)
            #pragma unroll
            for (int j = 0; j < 4; ++j) {
                float p = __expf(sc[si][j] - newm);
                sc[si][j] = p;
                tsum += p;
            }
        tsum += __shfl_xor(tsum, 16);
        tsum += __shfl_xor(tsum, 32);
        l_run = l_run * fac + tsum;
        m_run = newm;

        // write P (transposed into [a][s]) packed b64, swizzled
        #pragma unroll
        for (int si = 0; si < 4; ++si) {
            ushort4 h4, l4;
            bf_split(sc[si][0], h4.x, l4.x);
            bf_split(sc[si][1], h4.y, l4.y);
            bf_split(sc[si][2], h4.z, l4.z);
            bf_split(sc[si][3], h4.w, l4.w);
            int baseS = si * 16 + (hi4 << 2);
            int addr = al15 * 64 + (baseS ^ ((al15 & 7) << 3));
            *reinterpret_cast<ushort4*>(pwh + addr) = h4;
            *reinterpret_cast<ushort4*>(pwl + addr) = l4;
        }

        // rescale O
        float fj[4];
        #pragma unroll
        for (int j = 0; j < 4; ++j) fj[j] = __shfl(fac, (hi4 << 2) + j);
        #pragma unroll
        for (int di = 0; di < 4; ++di)
            #pragma unroll
            for (int j = 0; j < 4; ++j) O[di][j] *= fj[j];

        // PV: O[a][d] += P[a][s] * Vt[d][s]
        #pragma unroll
        for (int ks = 0; ks < 2; ++ks) {
            bf16x8 pah = fragR<64>(pwh, al15, ks, lane);
            bf16x8 pal = fragR<64>(pwl, al15, ks, lane);
            #pragma unroll
            for (int di = 0; di < 4; ++di) {
                bf16x8 vh = fragR<64>(vth, di * 16 + al15, ks, lane);
                bf16x8 vl = fragR<64>(vtl, di * 16 + al15, ks, lane);
                O[di] = __builtin_amdgcn_mfma_f32_16x16x32_bf16(pah, vh, O[di], 0, 0, 0);
                O[di] = __builtin_amdgcn_mfma_f32_16x16x32_bf16(pah, vl, O[di], 0, 0, 0);
                O[di] = __builtin_amdgcn_mfma_f32_16x16x32_bf16(pal, vh, O[di], 0, 0, 0);
            }
        }
        __syncthreads();
    }

    // epilogue: normalize, write avt in TILE layout (ushort4 over a&3)
    float lj[4];
    #pragma unroll
    for (int j = 0; j < 4; ++j) lj[j] = __shfl(l_run, (hi4 << 2) + j);
    #pragma unroll
    for (int di = 0; di < 4; ++di) {
        ushort4 h4, l4;
        #pragma unroll
        for (int j = 0; j < 4; ++j) {
            float val = O[di][j] / lj[j];
            unsigned short hi, lo;
            bf_split(val, hi, lo);
            ((unsigned short*)&h4)[j] = hi;
            ((unsigned short*)&l4)[j] = lo;
        }
        // d = di*16 + al15; a = a0 + w*16 + hi4*4 + j
        const size_t oidx = (size_t)bh * 16384
            + (size_t)(di * 8 + (a0 >> 5) + (w >> 1)) * 512
            + (size_t)((2 * w + (hi4 >> 1)) & 3) * 128
            + al15 * 8 + (hi4 & 1) * 4;
        *reinterpret_cast<ushort4*>(avt_hi + oidx) = h4;
        *reinterpret_cast<ushort4*>(avt_lo + oidx) = l4;
    }
}

// ---------- flash stage-2 (v4): all operands TILE-direct; per-wave fp32 P LDS; no barriers ----------
// grid (Ssz/64, B*H). block 256 (4 waves x 16 s-rows).
__global__ __launch_bounds__(256, 2)
void flash2(const unsigned short* __restrict__ qh_hi, const unsigned short* __restrict__ qh_lo,
            const unsigned short* __restrict__ ag_hi, const unsigned short* __restrict__ ag_lo,
            const unsigned short* __restrict__ avt_hi, const unsigned short* __restrict__ avt_lo,
            float* __restrict__ q_attn,
            unsigned short* __restrict__ xo_hi, unsigned short* __restrict__ xo_lo)
{
    __shared__ float plds[4][4096];   // per-wave [16 s][256 a] fp32, float4-XOR-swizzled (64 KB)

    const int t = threadIdx.x, lane = t & 63, w = t >> 6;
    const int al15 = lane & 15, hi4 = lane >> 4;
    const int bh = blockIdx.y;
    const int s0 = blockIdx.x * 64;
    float* P = plds[w];

    // qh fragments (B-operand): TILE-direct, coalesced
    bf16x8 bqh[2], bql[2];
    {
        const size_t qbase = (size_t)bh * 131072 + (size_t)((s0 >> 4) + w) * 1024;
        #pragma unroll
        for (int ks = 0; ks < 2; ++ks) {
            bqh[ks] = gfrag(qh_hi + qbase + ks * 512 + lane * 8);
            bql[ks] = gfrag(qh_lo + qbase + ks * 512 + lane * 8);
        }
    }

    // QK^T (swapped): acc[ai][j] = S[a = ai*16 + hi4*4 + j][s = al15]
    const unsigned short* agh = ag_hi + (size_t)bh * 16384;
    const unsigned short* agl = ag_lo + (size_t)bh * 16384;
    f32x4 acc[16];
    #pragma unroll
    for (int ai = 0; ai < 16; ++ai) acc[ai] = f32x4{0.f, 0.f, 0.f, 0.f};
    #pragma unroll
    for (int ai = 0; ai < 16; ++ai)
        #pragma unroll
        for (int ks = 0; ks < 2; ++ks) {
            bf16x8 ah = gfrag(agh + (ai * 2 + ks) * 512 + lane * 8);
            bf16x8 al = gfrag(agl + (ai * 2 + ks) * 512 + lane * 8);
            acc[ai] = __builtin_amdgcn_mfma_f32_16x16x32_bf16(ah, bqh[ks], acc[ai], 0, 0, 0);
            acc[ai] = __builtin_amdgcn_mfma_f32_16x16x32_bf16(ah, bql[ks], acc[ai], 0, 0, 0);
            acc[ai] = __builtin_amdgcn_mfma_f32_16x16x32_bf16(al, bqh[ks], acc[ai], 0, 0, 0);
        }

    // exact softmax over a for s = al15
    float mx = -INFINITY;
    #pragma unroll
    for (int ai = 0; ai < 16; ++ai)
        #pragma unroll
        for (int j = 0; j < 4; ++j) {
            acc[ai][j] *= 0.125f;
            mx = fmaxf(mx, acc[ai][j]);
        }
    mx = fmaxf(mx, __shfl_xor(mx, 16));
    mx = fmaxf(mx, __shfl_xor(mx, 32));
    float sum = 0.f;
    #pragma unroll
    for (int ai = 0; ai < 16; ++ai)
        #pragma unroll
        for (int j = 0; j < 4; ++j) {
            float p = __expf(acc[ai][j] - mx);
            acc[ai][j] = p;
            sum += p;
        }
    sum += __shfl_xor(sum, 16);
    sum += __shfl_xor(sum, 32);
    const float inv = 1.0f / sum;

    // normalized P -> per-wave LDS (fp32, float4-granular XOR swizzle)
    #pragma unroll
    for (int ai = 0; ai < 16; ++ai) {
        float4 o;
        o.x = acc[ai][0] * inv; o.y = acc[ai][1] * inv;
        o.z = acc[ai][2] * inv; o.w = acc[ai][3] * inv;
        int pos4 = (ai * 4 + hi4) ^ (al15 & 7);
        *reinterpret_cast<float4*>(P + al15 * 256 + pos4 * 4) = o;
    }

    // q_attn: coalesced full-row stores via LDS transpose
    {
        float* qbase = q_attn + ((size_t)bh * Ssz + s0 + w * 16) * An;
        #pragma unroll
        for (int r = 0; r < 16; ++r) {
            float4 f = *reinterpret_cast<const float4*>(P + r * 256 + ((lane ^ (r & 7)) * 4));
            *reinterpret_cast<float4*>(qbase + r * An + lane * 4) = f;
        }
    }

    // PV: O[s][d] = sum_a P[s][a] * avt[d][a]; avt TILE-direct
    const unsigned short* avh_b = avt_hi + (size_t)bh * 16384;
    const unsigned short* avl_b = avt_lo + (size_t)bh * 16384;
    f32x4 O[4];
    #pragma unroll
    for (int i = 0; i < 4; ++i) O[i] = f32x4{0.f, 0.f, 0.f, 0.f};
    #pragma unroll
    for (int ks = 0; ks < 8; ++ks) {
        int p4 = ks * 8 + hi4 * 2;
        float4 fa = *reinterpret_cast<const float4*>(P + al15 * 256 + ((p4 ^ (al15 & 7)) * 4));
        float4 fb = *reinterpret_cast<const float4*>(P + al15 * 256 + (((p4 + 1) ^ (al15 & 7)) * 4));
        bf16x8 pah, pal;
        make8(fa, fb, pah, pal);
        #pragma unroll
        for (int di = 0; di < 4; ++di) {
            bf16x8 avh = gfrag(avh_b + (di * 8 + ks) * 512 + lane * 8);
            bf16x8 avl = gfrag(avl_b + (di * 8 + ks) * 512 + lane * 8);
            O[di] = __builtin_amdgcn_mfma_f32_16x16x32_bf16(pah, avh, O[di], 0, 0, 0);
            O[di] = __builtin_amdgcn_mfma_f32_16x16x32_bf16(pah, avl, O[di], 0, 0, 0);
            O[di] = __builtin_amdgcn_mfma_f32_16x16x32_bf16(pal, avh, O[di], 0, 0, 0);
        }
    }

    // epilogue: out_h split bf16 into [B,S,D] head-merged
    const int b = bh >> 4, h = bh & (Hn - 1);
    #pragma unroll
    for (int di = 0; di < 4; ++di)
        #pragma unroll
        for (int j = 0; j < 4; ++j) {
            float val = O[di][j];
            int sG = s0 + w * 16 + (hi4 << 2) + j;
            int dfull = h * dh + di * 16 + al15;
            size_t idx = ((size_t)b * Ssz + sG) * Dsz + dfull;
            unsigned short hi, lo;
            bf_split(val, hi, lo);
            xo_hi[idx] = hi; xo_lo[idx] = lo;
        }
}

extern "C" void kernel_launch(void* const* d_in, const int* in_sizes, int n_in,
                              void* d_out, int out_size, void* d_ws, size_t ws_size,
                              hipStream_t stream)
{
    const float* q  = (const float*)d_in[0];
    const float* k  = (const float*)d_in[1];
    const float* v  = (const float*)d_in[2];
    const float* Wq = (const float*)d_in[3];
    const float* bq = (const float*)d_in[4];
    const float* Wk = (const float*)d_in[5];
    const float* bk = (const float*)d_in[6];
    const float* Wv = (const float*)d_in[7];
    const float* bv = (const float*)d_in[8];
    const float* Wo = (const float*)d_in[9];
    const float* bo = (const float*)d_in[10];

    constexpr size_t BSD = (size_t)Bsz * Ssz * Dsz;    // 8,388,608
    constexpr size_t DD  = (size_t)Dsz * Dsz;          // 1,048,576
    constexpr size_t AGD = (size_t)Bsz * Hn * An * dh; // 1,048,576

    float* out    = (float*)d_out;
    float* q_attn = out + BSD;

    unsigned short* u = (unsigned short*)d_ws;
    unsigned short* x_hi   = u;                 // [B,S,D] bf16 (out_h buffer)
    unsigned short* x_lo   = x_hi + BSD;
    unsigned short* qh_hi  = x_lo + BSD;        // qh TILE layout
    unsigned short* qh_lo  = qh_hi + BSD;
    unsigned short* kh_hi  = qh_lo + BSD;       // [B,H,S,dh] row-major
    unsigned short* kh_lo  = kh_hi + BSD;
    unsigned short* vt_hi  = kh_lo + BSD;       // [B,H,dh,S]
    unsigned short* vt_lo  = vt_hi + BSD;
    unsigned short* w_hi   = vt_lo + BSD;       // [D,D]
    unsigned short* w_lo   = w_hi + DD;
    unsigned short* ag_hi  = w_lo + DD;         // agents TILE layout
    unsigned short* ag_lo  = ag_hi + AGD;
    unsigned short* avt_hi = ag_lo + AGD;       // avt TILE layout
    unsigned short* avt_lo = avt_hi + AGD;

    const int M = Bsz * Ssz;                    // 8192
    dim3 gmfma(Dsz / MT, M / MT, 1);            // (8, 64)

    // Q projection (TILE output)
    split_kernel<<<BSD / 1024, 256, 0, stream>>>(q, x_hi, x_lo, BSD / 4);
    split_kernel<<<DD / 1024, 256, 0, stream>>>(Wq, w_hi, w_lo, DD / 4);
    gemm_nt_mfma3<3><<<gmfma, 256, 0, stream>>>(x_hi, x_lo, w_hi, w_lo, bq, nullptr, qh_hi, qh_lo, Dsz, Dsz);
    // K projection (row-major head-split)
    split_kernel<<<BSD / 1024, 256, 0, stream>>>(k, x_hi, x_lo, BSD / 4);
    split_kernel<<<DD / 1024, 256, 0, stream>>>(Wk, w_hi, w_lo, DD / 4);
    gemm_nt_mfma3<1><<<gmfma, 256, 0, stream>>>(x_hi, x_lo, w_hi, w_lo, bk, nullptr, kh_hi, kh_lo, Dsz, Dsz);
    // V projection (transposed head-split)
    split_kernel<<<BSD / 1024, 256, 0, stream>>>(v, x_hi, x_lo, BSD / 4);
    split_kernel<<<DD / 1024, 256, 0, stream>>>(Wv, w_hi, w_lo, DD / 4);
    gemm_nt_mfma3<2><<<gmfma, 256, 0, stream>>>(x_hi, x_lo, w_hi, w_lo, bv, nullptr, vt_hi, vt_lo, Dsz, Dsz);

    // agent pooling (tile in, tile out)
    pool_agent<<<AGD / 256, 256, 0, stream>>>(qh_hi, qh_lo, ag_hi, ag_lo);

    // stage 1: flash agent attention -> avt (tile)
    flash1<<<dim3(An / 64, Bsz * Hn), 256, 0, stream>>>(
        ag_hi, ag_lo, kh_hi, kh_lo, vt_hi, vt_lo, avt_hi, avt_lo);

    // stage 2: q attends agents -> q_attn + out_h
    flash2<<<dim3(Ssz / 64, Bsz * Hn), 256, 0, stream>>>(
        qh_hi, qh_lo, ag_hi, ag_lo, avt_hi, avt_lo, q_attn, x_hi, x_lo);

    // output projection
    split_kernel<<<DD / 1024, 256, 0, stream>>>(Wo, w_hi, w_lo, DD / 4);
    gemm_nt_mfma3<0><<<gmfma, 256, 0, stream>>>(x_hi, x_lo, w_hi, w_lo, bo, out, nullptr, nullptr, Dsz, Dsz);
}

// Round 7
// 415.807 us; speedup vs baseline: 1.2728x; 1.0022x over previous
//
#include <hip/hip_runtime.h>

// Problem constants
constexpr int Bsz = 4, Ssz = 2048, Dsz = 1024, Hn = 16, dh = 64, An = 256;

typedef __attribute__((ext_vector_type(8))) short bf16x8;
typedef __attribute__((ext_vector_type(4))) float f32x4;

// ---------- helpers ----------
__device__ __forceinline__ unsigned short f2bf_rn(float f) {
    unsigned int u = __float_as_uint(f);
    return (unsigned short)((u + 0x7FFFu + ((u >> 16) & 1u)) >> 16);
}
__device__ __forceinline__ float bf2f(unsigned short h) {
    return __uint_as_float(((unsigned int)h) << 16);
}
__device__ __forceinline__ void bf_split(float f, unsigned short& hi, unsigned short& lo) {
    hi = f2bf_rn(f);
    lo = f2bf_rn(f - bf2f(hi));
}
__device__ __forceinline__ void gload16(const unsigned short* g, unsigned short* l) {
    __builtin_amdgcn_global_load_lds(
        (const __attribute__((address_space(1))) unsigned int*)g,
        (__attribute__((address_space(3))) unsigned int*)l, 16, 0, 0);
}
__device__ __forceinline__ bf16x8 gfrag(const unsigned short* g) {
    return *reinterpret_cast<const bf16x8*>(g);
}
// split 8 fp32 (two float4) into hi/lo bf16x8 fragments
__device__ __forceinline__ void make8(float4 a, float4 b, bf16x8& hi8, bf16x8& lo8) {
    float v[8] = {a.x, a.y, a.z, a.w, b.x, b.y, b.z, b.w};
    #pragma unroll
    for (int i = 0; i < 8; ++i) {
        unsigned short h, l;
        bf_split(v[i], h, l);
        hi8[i] = (short)h; lo8[i] = (short)l;
    }
}

// Fragment-tile layout (per bh): element (row, k) of a [R][64] operand lives at
//   tile(row>>4, k>>5)*512 + ((k>>3)&3)*128 + (row&15)*8 + (k&7)
// so an MFMA fragment load = base + lane*8, one contiguous 1KB wave transaction.

// Stage a row-major tile into linear LDS with source-side chunk swizzle.
template<int LOGC, int NISS>
__device__ __forceinline__ void stage_tile(const unsigned short* __restrict__ g, long rowStride,
                                           unsigned short* lbase, int t) {
    const int wid = t >> 6;
    #pragma unroll
    for (int i = 0; i < NISS; ++i) {
        int slot = i * 256 + t;
        int r = slot >> LOGC;
        int c = slot & ((1 << LOGC) - 1);
        int cs = (c ^ (r & 7)) & ((1 << LOGC) - 1);
        gload16(g + (long)r * rowStride + cs * 8, lbase + (i * 256 + wid * 64) * 8);
    }
}
template<int ROWLEN>
__device__ __forceinline__ bf16x8 fragR(const unsigned short* buf, int row, int ks, int lane) {
    int c = ks * 4 + (lane >> 4);
    int cs = (c ^ (row & 7)) & (ROWLEN / 8 - 1);
    return *reinterpret_cast<const bf16x8*>(buf + row * ROWLEN + cs * 8);
}

// fp32 [n4*4] -> bf16 hi/lo arrays
__global__ __launch_bounds__(256)
void split_kernel(const float* __restrict__ x, unsigned short* __restrict__ hi,
                  unsigned short* __restrict__ lo, int n4)
{
    int i = blockIdx.x * 256 + threadIdx.x;
    if (i >= n4) return;
    float4 v = reinterpret_cast<const float4*>(x)[i];
    ushort4 h, l;
    bf_split(v.x, h.x, l.x);
    bf_split(v.y, h.y, l.y);
    bf_split(v.z, h.z, l.z);
    bf_split(v.w, h.w, l.w);
    reinterpret_cast<ushort4*>(hi)[i] = h;
    reinterpret_cast<ushort4*>(lo)[i] = l;
}

// ---------- split-bf16 MFMA GEMM ----------
// OMODE 0: fp32 flat. 1: bf16-split [B,H,S,dh]. 2: bf16-split [B,H,dh,S]. 3: bf16-split TILE (qh).
#define MT 128
#define BKm 32

__device__ __forceinline__ bf16x8 lds_frag(const unsigned short* buf, int baseRow, int lane) {
    int row = baseRow + (lane & 15);
    int c = lane >> 4;
    int idx = row * 32 + ((c ^ ((row >> 1) & 3)) << 3);
    return *reinterpret_cast<const bf16x8*>(buf + idx);
}

template<int OMODE>
__global__ __launch_bounds__(256, 2)
void gemm_nt_mfma3(const unsigned short* __restrict__ Ahi, const unsigned short* __restrict__ Alo,
                   const unsigned short* __restrict__ Bhi, const unsigned short* __restrict__ Blo,
                   const float* __restrict__ bias, float* __restrict__ Cf,
                   unsigned short* __restrict__ Chi, unsigned short* __restrict__ Clo,
                   int K, int N)
{
    __shared__ unsigned short lds[4 * 4096];
    const int t = threadIdx.x;
    const int lane = t & 63, wid = t >> 6;
    const int wr = wid >> 1, wc = wid & 1;
    const int m0 = blockIdx.y * MT, n0 = blockIdx.x * MT;

    const int srow0 = t >> 2;
    const int x4 = t & 3;
    const int ldsBase0 = (wid * 64) * 8;
    const int ldsBase1 = (256 + wid * 64) * 8;

    f32x4 acc[4][4];
    #pragma unroll
    for (int i = 0; i < 4; ++i)
        #pragma unroll
        for (int j = 0; j < 4; ++j)
            acc[i][j] = f32x4{0.f, 0.f, 0.f, 0.f};

    const unsigned short* gA[2] = {Ahi, Alo};
    const unsigned short* gB[2] = {Bhi, Blo};

    for (int k0 = 0; k0 < K; k0 += BKm) {
        #pragma unroll
        for (int hb = 0; hb < 2; ++hb) {
            {
                const unsigned short* G = gA[hb];
                int r0 = srow0, r1 = srow0 + 64;
                int c0 = x4 ^ ((r0 >> 1) & 3);
                int c1 = x4 ^ ((r1 >> 1) & 3);
                gload16(G + (size_t)(m0 + r0) * K + k0 + c0 * 8, lds + hb * 4096 + ldsBase0);
                gload16(G + (size_t)(m0 + r1) * K + k0 + c1 * 8, lds + hb * 4096 + ldsBase1);
            }
            {
                const unsigned short* G = gB[hb];
                int r0 = srow0, r1 = srow0 + 64;
                int c0 = x4 ^ ((r0 >> 1) & 3);
                int c1 = x4 ^ ((r1 >> 1) & 3);
                gload16(G + (size_t)(n0 + r0) * K + k0 + c0 * 8, lds + (2 + hb) * 4096 + ldsBase0);
                gload16(G + (size_t)(n0 + r1) * K + k0 + c1 * 8, lds + (2 + hb) * 4096 + ldsBase1);
            }
        }
        __syncthreads();

        bf16x8 ah[4], al[4], bh[4], bl[4];
        #pragma unroll
        for (int mi = 0; mi < 4; ++mi) {
            ah[mi] = lds_frag(lds + 0 * 4096, wr * 64 + mi * 16, lane);
            al[mi] = lds_frag(lds + 1 * 4096, wr * 64 + mi * 16, lane);
        }
        #pragma unroll
        for (int ni = 0; ni < 4; ++ni) {
            bh[ni] = lds_frag(lds + 2 * 4096, wc * 64 + ni * 16, lane);
            bl[ni] = lds_frag(lds + 3 * 4096, wc * 64 + ni * 16, lane);
        }
        #pragma unroll
        for (int mi = 0; mi < 4; ++mi)
            #pragma unroll
            for (int ni = 0; ni < 4; ++ni) {
                acc[mi][ni] = __builtin_amdgcn_mfma_f32_16x16x32_bf16(ah[mi], bh[ni], acc[mi][ni], 0, 0, 0);
                acc[mi][ni] = __builtin_amdgcn_mfma_f32_16x16x32_bf16(ah[mi], bl[ni], acc[mi][ni], 0, 0, 0);
                acc[mi][ni] = __builtin_amdgcn_mfma_f32_16x16x32_bf16(al[mi], bh[ni], acc[mi][ni], 0, 0, 0);
            }
        __syncthreads();
    }

    #pragma unroll
    for (int mi = 0; mi < 4; ++mi) {
        #pragma unroll
        for (int ni = 0; ni < 4; ++ni) {
            const int n = n0 + wc * 64 + ni * 16 + (lane & 15);
            const float bval = bias[n];
            #pragma unroll
            for (int j = 0; j < 4; ++j) {
                const int m = m0 + wr * 64 + mi * 16 + ((lane >> 4) << 2) + j;
                float val = acc[mi][ni][j] + bval;
                if constexpr (OMODE == 0) {
                    Cf[(size_t)m * N + n] = val;
                } else {
                    const int b = m >> 11, s = m & (Ssz - 1);
                    const int h = n >> 6, c = n & (dh - 1);
                    size_t idx;
                    if constexpr (OMODE == 1)
                        idx = (((size_t)(b * Hn + h)) * Ssz + s) * dh + c;
                    else if constexpr (OMODE == 2)
                        idx = (((size_t)(b * Hn + h)) * dh + c) * Ssz + s;
                    else  // 3: fragment-tile layout for qh
                        idx = (size_t)(b * Hn + h) * 131072
                            + (((s >> 4) * 2 + (c >> 5)) << 9)
                            + (((c >> 3) & 3) << 7) + ((s & 15) << 3) + (c & 7);
                    unsigned short hi, lo;
                    bf_split(val, hi, lo);
                    Chi[idx] = hi; Clo[idx] = lo;
                }
            }
        }
    }
}

// ---------- agent pooling: reads qh TILE, writes agents TILE ----------
__global__ __launch_bounds__(256)
void pool_agent(const unsigned short* __restrict__ qh_hi, const unsigned short* __restrict__ qh_lo,
                unsigned short* __restrict__ ag_hi, unsigned short* __restrict__ ag_lo)
{
    const int idx = blockIdx.x * 256 + threadIdx.x;
    const int c = idx & (dh - 1);
    const int a = (idx >> 6) & (An - 1);
    const int bh = idx >> 14;
    // qh tile address of (s = a*8, c)
    const size_t base = (size_t)bh * 131072
        + (((a >> 1) * 2 + (c >> 5)) << 9) + (((c >> 3) & 3) << 7)
        + ((8 * (a & 1)) << 3) + (c & 7);
    float s = 0.f;
    #pragma unroll
    for (int j = 0; j < 8; ++j)
        s += bf2f(qh_hi[base + j * 8]) + bf2f(qh_lo[base + j * 8]);
    s *= 0.125f;
    unsigned short hi, lo;
    bf_split(s, hi, lo);
    const size_t oidx = (size_t)bh * 16384
        + (((a >> 4) * 2 + (c >> 5)) << 9) + (((c >> 3) & 3) << 7)
        + ((a & 15) << 3) + (c & 7);
    ag_hi[oidx] = hi; ag_lo[oidx] = lo;
}

// ---------- flash stage-1: 64-agent blocks, K/V LDS-staged, agents TILE-direct ----------
// grid (An/64, B*H) = (4, 64). block 256 (4 waves x 16 agents).
__global__ __launch_bounds__(256, 3)
void flash1(const unsigned short* __restrict__ ag_hi, const unsigned short* __restrict__ ag_lo,
            const unsigned short* __restrict__ kh_hi, const unsigned short* __restrict__ kh_lo,
            const unsigned short* __restrict__ vt_hi_g, const unsigned short* __restrict__ vt_lo_g,
            unsigned short* __restrict__ avt_hi, unsigned short* __restrict__ avt_lo)
{
    __shared__ unsigned short lds[24576];   // 48 KB
    unsigned short* kth = lds;              // [64][64]
    unsigned short* ktl = lds + 4096;
    unsigned short* vth = lds + 8192;       // [64 d][64 s]
    unsigned short* vtl = lds + 12288;
    const int t = threadIdx.x;
    const int lane = t & 63, w = t >> 6;
    const int al15 = lane & 15, hi4 = lane >> 4;
    unsigned short* pwh = lds + 16384 + w * 2048;   // per-wave P [16 a][64 s]
    unsigned short* pwl = pwh + 1024;

    const int bh = blockIdx.y;
    const int a0 = blockIdx.x * 64;

    // agent fragments: direct from TILE layout (coalesced 1KB loads)
    bf16x8 bqh[2], bql[2];
    {
        const size_t abase = (size_t)bh * 16384 + (size_t)((a0 >> 4) + w) * 1024;
        #pragma unroll
        for (int ks = 0; ks < 2; ++ks) {
            bqh[ks] = gfrag(ag_hi + abase + ks * 512 + lane * 8);
            bql[ks] = gfrag(ag_lo + abase + ks * 512 + lane * 8);
        }
    }

    f32x4 O[4];
    #pragma unroll
    for (int i = 0; i < 4; ++i) O[i] = f32x4{0.f, 0.f, 0.f, 0.f};
    float m_run = -INFINITY, l_run = 0.f;

    for (int s0 = 0; s0 < Ssz; s0 += 64) {
        stage_tile<3, 2>(kh_hi + ((size_t)bh * Ssz + s0) * dh, dh, kth, t);
        stage_tile<3, 2>(kh_lo + ((size_t)bh * Ssz + s0) * dh, dh, ktl, t);
        stage_tile<3, 2>(vt_hi_g + (size_t)bh * dh * Ssz + s0, Ssz, vth, t);
        stage_tile<3, 2>(vt_lo_g + (size_t)bh * dh * Ssz + s0, Ssz, vtl, t);
        __syncthreads();

        // QK^T (swapped): acc col = agent (lane&15), row = s
        f32x4 sc[4];
        #pragma unroll
        for (int si = 0; si < 4; ++si) sc[si] = f32x4{0.f, 0.f, 0.f, 0.f};
        #pragma unroll
        for (int si = 0; si < 4; ++si)
            #pragma unroll
            for (int ks = 0; ks < 2; ++ks) {
                bf16x8 ah = fragR<64>(kth, si * 16 + al15, ks, lane);
                bf16x8 al = fragR<64>(ktl, si * 16 + al15, ks, lane);
                sc[si] = __builtin_amdgcn_mfma_f32_16x16x32_bf16(ah, bqh[ks], sc[si], 0, 0, 0);
                sc[si] = __builtin_amdgcn_mfma_f32_16x16x32_bf16(ah, bql[ks], sc[si], 0, 0, 0);
                sc[si] = __builtin_amdgcn_mfma_f32_16x16x32_bf16(al, bqh[ks], sc[si], 0, 0, 0);
            }

        // online softmax over s for agent = lane&15
        float tmax = -INFINITY;
        #pragma unroll
        for (int si = 0; si < 4; ++si)
            #pragma unroll
            for (int j = 0; j < 4; ++j) {
                sc[si][j] *= 0.125f;
                tmax = fmaxf(tmax, sc[si][j]);
            }
        tmax = fmaxf(tmax, __shfl_xor(tmax, 16));
        tmax = fmaxf(tmax, __shfl_xor(tmax, 32));
        float newm = fmaxf(m_run, tmax);
        float fac = __expf(m_run - newm);
        float tsum = 0.f;
        #pragma unroll
        for (int si = 0; si < 4; ++si)
            #pragma unroll
            for (int j = 0; j < 4; ++j) {
                float p = __expf(sc[si][j] - newm);
                sc[si][j] = p;
                tsum += p;
            }
        tsum += __shfl_xor(tsum, 16);
        tsum += __shfl_xor(tsum, 32);
        l_run = l_run * fac + tsum;
        m_run = newm;

        // write P (transposed into [a][s]) packed b64, swizzled
        #pragma unroll
        for (int si = 0; si < 4; ++si) {
            ushort4 h4, l4;
            bf_split(sc[si][0], h4.x, l4.x);
            bf_split(sc[si][1], h4.y, l4.y);
            bf_split(sc[si][2], h4.z, l4.z);
            bf_split(sc[si][3], h4.w, l4.w);
            int baseS = si * 16 + (hi4 << 2);
            int addr = al15 * 64 + (baseS ^ ((al15 & 7) << 3));
            *reinterpret_cast<ushort4*>(pwh + addr) = h4;
            *reinterpret_cast<ushort4*>(pwl + addr) = l4;
        }

        // rescale O
        float fj[4];
        #pragma unroll
        for (int j = 0; j < 4; ++j) fj[j] = __shfl(fac, (hi4 << 2) + j);
        #pragma unroll
        for (int di = 0; di < 4; ++di)
            #pragma unroll
            for (int j = 0; j < 4; ++j) O[di][j] *= fj[j];

        // PV: O[a][d] += P[a][s] * Vt[d][s]
        #pragma unroll
        for (int ks = 0; ks < 2; ++ks) {
            bf16x8 pah = fragR<64>(pwh, al15, ks, lane);
            bf16x8 pal = fragR<64>(pwl, al15, ks, lane);
            #pragma unroll
            for (int di = 0; di < 4; ++di) {
                bf16x8 vh = fragR<64>(vth, di * 16 + al15, ks, lane);
                bf16x8 vl = fragR<64>(vtl, di * 16 + al15, ks, lane);
                O[di] = __builtin_amdgcn_mfma_f32_16x16x32_bf16(pah, vh, O[di], 0, 0, 0);
                O[di] = __builtin_amdgcn_mfma_f32_16x16x32_bf16(pah, vl, O[di], 0, 0, 0);
                O[di] = __builtin_amdgcn_mfma_f32_16x16x32_bf16(pal, vh, O[di], 0, 0, 0);
            }
        }
        __syncthreads();
    }

    // epilogue: normalize, write avt in TILE layout (ushort4 over a&3)
    float lj[4];
    #pragma unroll
    for (int j = 0; j < 4; ++j) lj[j] = __shfl(l_run, (hi4 << 2) + j);
    #pragma unroll
    for (int di = 0; di < 4; ++di) {
        ushort4 h4, l4;
        #pragma unroll
        for (int j = 0; j < 4; ++j) {
            float val = O[di][j] / lj[j];
            unsigned short hi, lo;
            bf_split(val, hi, lo);
            ((unsigned short*)&h4)[j] = hi;
            ((unsigned short*)&l4)[j] = lo;
        }
        // d = di*16 + al15; a = a0 + w*16 + hi4*4 + j
        const size_t oidx = (size_t)bh * 16384
            + (size_t)(di * 8 + (a0 >> 5) + (w >> 1)) * 512
            + (size_t)((2 * w + (hi4 >> 1)) & 3) * 128
            + al15 * 8 + (hi4 & 1) * 4;
        *reinterpret_cast<ushort4*>(avt_hi + oidx) = h4;
        *reinterpret_cast<ushort4*>(avt_lo + oidx) = l4;
    }
}

// ---------- flash stage-2 (v4): all operands TILE-direct; per-wave fp32 P LDS; no barriers ----------
// grid (Ssz/64, B*H). block 256 (4 waves x 16 s-rows).
__global__ __launch_bounds__(256, 2)
void flash2(const unsigned short* __restrict__ qh_hi, const unsigned short* __restrict__ qh_lo,
            const unsigned short* __restrict__ ag_hi, const unsigned short* __restrict__ ag_lo,
            const unsigned short* __restrict__ avt_hi, const unsigned short* __restrict__ avt_lo,
            float* __restrict__ q_attn,
            unsigned short* __restrict__ xo_hi, unsigned short* __restrict__ xo_lo)
{
    __shared__ float plds[4][4096];   // per-wave [16 s][256 a] fp32, float4-XOR-swizzled (64 KB)

    const int t = threadIdx.x, lane = t & 63, w = t >> 6;
    const int al15 = lane & 15, hi4 = lane >> 4;
    const int bh = blockIdx.y;
    const int s0 = blockIdx.x * 64;
    float* P = plds[w];

    // qh fragments (B-operand): TILE-direct, coalesced
    bf16x8 bqh[2], bql[2];
    {
        const size_t qbase = (size_t)bh * 131072 + (size_t)((s0 >> 4) + w) * 1024;
        #pragma unroll
        for (int ks = 0; ks < 2; ++ks) {
            bqh[ks] = gfrag(qh_hi + qbase + ks * 512 + lane * 8);
            bql[ks] = gfrag(qh_lo + qbase + ks * 512 + lane * 8);
        }
    }

    // QK^T (swapped): acc[ai][j] = S[a = ai*16 + hi4*4 + j][s = al15]
    const unsigned short* agh = ag_hi + (size_t)bh * 16384;
    const unsigned short* agl = ag_lo + (size_t)bh * 16384;
    f32x4 acc[16];
    #pragma unroll
    for (int ai = 0; ai < 16; ++ai) acc[ai] = f32x4{0.f, 0.f, 0.f, 0.f};
    #pragma unroll
    for (int ai = 0; ai < 16; ++ai)
        #pragma unroll
        for (int ks = 0; ks < 2; ++ks) {
            bf16x8 ah = gfrag(agh + (ai * 2 + ks) * 512 + lane * 8);
            bf16x8 al = gfrag(agl + (ai * 2 + ks) * 512 + lane * 8);
            acc[ai] = __builtin_amdgcn_mfma_f32_16x16x32_bf16(ah, bqh[ks], acc[ai], 0, 0, 0);
            acc[ai] = __builtin_amdgcn_mfma_f32_16x16x32_bf16(ah, bql[ks], acc[ai], 0, 0, 0);
            acc[ai] = __builtin_amdgcn_mfma_f32_16x16x32_bf16(al, bqh[ks], acc[ai], 0, 0, 0);
        }

    // exact softmax over a for s = al15
    float mx = -INFINITY;
    #pragma unroll
    for (int ai = 0; ai < 16; ++ai)
        #pragma unroll
        for (int j = 0; j < 4; ++j) {
            acc[ai][j] *= 0.125f;
            mx = fmaxf(mx, acc[ai][j]);
        }
    mx = fmaxf(mx, __shfl_xor(mx, 16));
    mx = fmaxf(mx, __shfl_xor(mx, 32));
    float sum = 0.f;
    #pragma unroll
    for (int ai = 0; ai < 16; ++ai)
        #pragma unroll
        for (int j = 0; j < 4; ++j) {
            float p = __expf(acc[ai][j] - mx);
            acc[ai][j] = p;
            sum += p;
        }
    sum += __shfl_xor(sum, 16);
    sum += __shfl_xor(sum, 32);
    const float inv = 1.0f / sum;

    // normalized P -> per-wave LDS (fp32, float4-granular XOR swizzle)
    #pragma unroll
    for (int ai = 0; ai < 16; ++ai) {
        float4 o;
        o.x = acc[ai][0] * inv; o.y = acc[ai][1] * inv;
        o.z = acc[ai][2] * inv; o.w = acc[ai][3] * inv;
        int pos4 = (ai * 4 + hi4) ^ (al15 & 7);
        *reinterpret_cast<float4*>(P + al15 * 256 + pos4 * 4) = o;
    }

    // q_attn: coalesced full-row stores via LDS transpose
    {
        float* qbase = q_attn + ((size_t)bh * Ssz + s0 + w * 16) * An;
        #pragma unroll
        for (int r = 0; r < 16; ++r) {
            float4 f = *reinterpret_cast<const float4*>(P + r * 256 + ((lane ^ (r & 7)) * 4));
            *reinterpret_cast<float4*>(qbase + r * An + lane * 4) = f;
        }
    }

    // PV: O[s][d] = sum_a P[s][a] * avt[d][a]; avt TILE-direct
    const unsigned short* avh_b = avt_hi + (size_t)bh * 16384;
    const unsigned short* avl_b = avt_lo + (size_t)bh * 16384;
    f32x4 O[4];
    #pragma unroll
    for (int i = 0; i < 4; ++i) O[i] = f32x4{0.f, 0.f, 0.f, 0.f};
    #pragma unroll
    for (int ks = 0; ks < 8; ++ks) {
        int p4 = ks * 8 + hi4 * 2;
        float4 fa = *reinterpret_cast<const float4*>(P + al15 * 256 + ((p4 ^ (al15 & 7)) * 4));
        float4 fb = *reinterpret_cast<const float4*>(P + al15 * 256 + (((p4 + 1) ^ (al15 & 7)) * 4));
        bf16x8 pah, pal;
        make8(fa, fb, pah, pal);
        #pragma unroll
        for (int di = 0; di < 4; ++di) {
            bf16x8 avh = gfrag(avh_b + (di * 8 + ks) * 512 + lane * 8);
            bf16x8 avl = gfrag(avl_b + (di * 8 + ks) * 512 + lane * 8);
            O[di] = __builtin_amdgcn_mfma_f32_16x16x32_bf16(pah, avh, O[di], 0, 0, 0);
            O[di] = __builtin_amdgcn_mfma_f32_16x16x32_bf16(pah, avl, O[di], 0, 0, 0);
            O[di] = __builtin_amdgcn_mfma_f32_16x16x32_bf16(pal, avh, O[di], 0, 0, 0);
        }
    }

    // epilogue: out_h split bf16 into [B,S,D] head-merged
    const int b = bh >> 4, h = bh & (Hn - 1);
    #pragma unroll
    for (int di = 0; di < 4; ++di)
        #pragma unroll
        for (int j = 0; j < 4; ++j) {
            float val = O[di][j];
            int sG = s0 + w * 16 + (hi4 << 2) + j;
            int dfull = h * dh + di * 16 + al15;
            size_t idx = ((size_t)b * Ssz + sG) * Dsz + dfull;
            unsigned short hi, lo;
            bf_split(val, hi, lo);
            xo_hi[idx] = hi; xo_lo[idx] = lo;
        }
}

extern "C" void kernel_launch(void* const* d_in, const int* in_sizes, int n_in,
                              void* d_out, int out_size, void* d_ws, size_t ws_size,
                              hipStream_t stream)
{
    const float* q  = (const float*)d_in[0];
    const float* k  = (const float*)d_in[1];
    const float* v  = (const float*)d_in[2];
    const float* Wq = (const float*)d_in[3];
    const float* bq = (const float*)d_in[4];
    const float* Wk = (const float*)d_in[5];
    const float* bk = (const float*)d_in[6];
    const float* Wv = (const float*)d_in[7];
    const float* bv = (const float*)d_in[8];
    const float* Wo = (const float*)d_in[9];
    const float* bo = (const float*)d_in[10];

    constexpr size_t BSD = (size_t)Bsz * Ssz * Dsz;    // 8,388,608
    constexpr size_t DD  = (size_t)Dsz * Dsz;          // 1,048,576
    constexpr size_t AGD = (size_t)Bsz * Hn * An * dh; // 1,048,576

    float* out    = (float*)d_out;
    float* q_attn = out + BSD;

    unsigned short* u = (unsigned short*)d_ws;
    unsigned short* x_hi   = u;                 // [B,S,D] bf16 (out_h buffer)
    unsigned short* x_lo   = x_hi + BSD;
    unsigned short* qh_hi  = x_lo + BSD;        // qh TILE layout
    unsigned short* qh_lo  = qh_hi + BSD;
    unsigned short* kh_hi  = qh_lo + BSD;       // [B,H,S,dh] row-major
    unsigned short* kh_lo  = kh_hi + BSD;
    unsigned short* vt_hi  = kh_lo + BSD;       // [B,H,dh,S]
    unsigned short* vt_lo  = vt_hi + BSD;
    unsigned short* w_hi   = vt_lo + BSD;       // [D,D]
    unsigned short* w_lo   = w_hi + DD;
    unsigned short* ag_hi  = w_lo + DD;         // agents TILE layout
    unsigned short* ag_lo  = ag_hi + AGD;
    unsigned short* avt_hi = ag_lo + AGD;       // avt TILE layout
    unsigned short* avt_lo = avt_hi + AGD;

    const int M = Bsz * Ssz;                    // 8192
    dim3 gmfma(Dsz / MT, M / MT, 1);            // (8, 64)

    // Q projection (TILE output)
    split_kernel<<<BSD / 1024, 256, 0, stream>>>(q, x_hi, x_lo, BSD / 4);
    split_kernel<<<DD / 1024, 256, 0, stream>>>(Wq, w_hi, w_lo, DD / 4);
    gemm_nt_mfma3<3><<<gmfma, 256, 0, stream>>>(x_hi, x_lo, w_hi, w_lo, bq, nullptr, qh_hi, qh_lo, Dsz, Dsz);
    // K projection (row-major head-split)
    split_kernel<<<BSD / 1024, 256, 0, stream>>>(k, x_hi, x_lo, BSD / 4);
    split_kernel<<<DD / 1024, 256, 0, stream>>>(Wk, w_hi, w_lo, DD / 4);
    gemm_nt_mfma3<1><<<gmfma, 256, 0, stream>>>(x_hi, x_lo, w_hi, w_lo, bk, nullptr, kh_hi, kh_lo, Dsz, Dsz);
    // V projection (transposed head-split)
    split_kernel<<<BSD / 1024, 256, 0, stream>>>(v, x_hi, x_lo, BSD / 4);
    split_kernel<<<DD / 1024, 256, 0, stream>>>(Wv, w_hi, w_lo, DD / 4);
    gemm_nt_mfma3<2><<<gmfma, 256, 0, stream>>>(x_hi, x_lo, w_hi, w_lo, bv, nullptr, vt_hi, vt_lo, Dsz, Dsz);

    // agent pooling (tile in, tile out)
    pool_agent<<<AGD / 256, 256, 0, stream>>>(qh_hi, qh_lo, ag_hi, ag_lo);

    // stage 1: flash agent attention -> avt (tile)
    flash1<<<dim3(An / 64, Bsz * Hn), 256, 0, stream>>>(
        ag_hi, ag_lo, kh_hi, kh_lo, vt_hi, vt_lo, avt_hi, avt_lo);

    // stage 2: q attends agents -> q_attn + out_h
    flash2<<<dim3(Ssz / 64, Bsz * Hn), 256, 0, stream>>>(
        qh_hi, qh_lo, ag_hi, ag_lo, avt_hi, avt_lo, q_attn, x_hi, x_lo);

    // output projection
    split_kernel<<<DD / 1024, 256, 0, stream>>>(Wo, w_hi, w_lo, DD / 4);
    gemm_nt_mfma3<0><<<gmfma, 256, 0, stream>>>(x_hi, x_lo, w_hi, w_lo, bo, out, nullptr, nullptr, Dsz, Dsz);
}